// Round 6
// baseline (570.333 us; speedup 1.0000x reference)
//
#include <hip/hip_runtime.h>
#include <hip/hip_bf16.h>
#include <math.h>

#define HID   128
#define NNODE 50000
#define NEDGE 800000
#define EB    64
#define PX    136   // edge/intermediate pitch (shorts) = 68 dwords = 34 float2 = 17 float4
#define PN    392   // node featA pitch (shorts): [h | agg_hi | agg_lo]

typedef __attribute__((ext_vector_type(8))) short short8;
typedef __attribute__((ext_vector_type(4))) float f32x4;

__device__ __forceinline__ float2 silu2(float x, float y) {
    return make_float2(x * __builtin_amdgcn_rcpf(1.0f + __expf(-x)),
                       y * __builtin_amdgcn_rcpf(1.0f + __expf(-y)));
}
__device__ __forceinline__ unsigned int pkbf(float2 v) {   // packed RNE f32x2 -> bf16x2
    __hip_bfloat162 b2 = __float22bfloat162_rn(v);
    return *(unsigned int*)&b2;
}
__device__ __forceinline__ unsigned short f2bf(float f) {  // scalar RNE
    unsigned int u = __float_as_uint(f);
    u += 0x7FFFu + ((u >> 16) & 1u);
    return (unsigned short)(u >> 16);
}
__device__ __forceinline__ float bf2f(unsigned short s) {
    return __uint_as_float(((unsigned int)s) << 16);
}
// physical col p (in a 128-wide interleaved buffer) -> logical col
__device__ __forceinline__ int permk(int p) {
    return (p & ~31) | ((p & 31) >> 1) | ((p & 1) << 4);
}

// ws layout (bytes)
#define WS_HBF  270336
#define WS_DEG  13070336
#define WS_ROW  13270336
#define WS_CUR  13470336
#define WS_BSUM 13670336
#define WS_RC2  13671360
#define WS_EAP  20071360

// ------------------------------------------------------------------ prep
__global__ void egnn_prep(const float* eW1, const float* eW2, const float* cW1,
                          const float* nW1, const float* nW2, const float* h,
                          const float* pos,
                          short* wsw, short* hbf, int* deg, float* out)
{
    int g = blockIdx.x * 256 + threadIdx.x;
    if (g < 16896) {
        const float* src; short* dst; int u, Kr, KC, mode;
        if (g < 4608)       { src = eW1; dst = wsw;            u = g;         Kr = 258; KC = 9;  mode = 0; }
        else if (g < 6656)  { src = eW2; dst = wsw + 4608*8;   u = g - 4608;  Kr = 128; KC = 4;  mode = 1; }
        else if (g < 8704)  { src = cW1; dst = wsw + 6656*8;   u = g - 6656;  Kr = 128; KC = 4;  mode = 1; }
        else if (g < 14848) { src = nW1; dst = wsw + 8704*8;   u = g - 8704;  Kr = 384; KC = 12; mode = 2; }
        else                { src = nW2; dst = wsw + 14848*8;  u = g - 14848; Kr = 128; KC = 4;  mode = 1; }
        int nt   = u / (KC * 64);
        int rem  = u % (KC * 64);
        int kc   = rem >> 6;
        int lane = rem & 63;
        int n    = nt * 16 + (lane & 15);
        int kb   = kc * 32 + ((lane >> 4) & 3) * 8;
        short8 o;
#pragma unroll
        for (int j = 0; j < 8; ++j) {
            int k = kb + j;
            int ks;
            if (mode == 0)      ks = k;
            else if (mode == 1) ks = permk(k);
            else {              // nW1: h natural, agg hi/lo permuted (lo reuses same rows)
                if (k < 128)      ks = k;
                else if (k < 256) ks = 128 + permk(k - 128);
                else              ks = 128 + permk(k - 256);
            }
            float v = (k < Kr) ? src[(long)ks * HID + n] : 0.0f;
            o[j] = (short)f2bf(v);
        }
        *(short8*)&dst[(long)u * 8] = o;
    } else if (g < 816896) {                       // h -> bf16
        long i = (long)(g - 16896) * 8;
        const float4 v0 = *(const float4*)&h[i];
        const float4 v1 = *(const float4*)&h[i + 4];
        uint4 o;
        o.x = pkbf(make_float2(v0.x, v0.y));
        o.y = pkbf(make_float2(v0.z, v0.w));
        o.z = pkbf(make_float2(v1.x, v1.y));
        o.w = pkbf(make_float2(v1.z, v1.w));
        *(uint4*)&hbf[i] = o;
    } else if (g < 2416896) {                      // zero agg region
        long i = (long)(g - 816896);
        ((float4*)out)[i] = make_float4(0.f, 0.f, 0.f, 0.f);
    } else if (g < 2566896) {                      // pos -> outpos
        int i = g - 2416896;
        out[(long)NNODE * HID + i] = pos[i];
    } else if (g < 2616896) {                      // zero deg
        int i = g - 2566896;
        deg[i] = 0;
    }
}

// ------------------------------------------------------------------ CSR build
__global__ void egnn_hist(const int* eidx, int* deg)
{
    int i = blockIdx.x * 256 + threadIdx.x;
    if (i < NEDGE / 4) {
        int4 v = ((const int4*)eidx)[i];
        atomicAdd(&deg[v.x], 1); atomicAdd(&deg[v.y], 1);
        atomicAdd(&deg[v.z], 1); atomicAdd(&deg[v.w], 1);
    }
}
__global__ void egnn_scan1(const int* deg, int* rowptr, int* bsum)
{
    __shared__ int s[256];
    int t = threadIdx.x, i = blockIdx.x * 256 + t;
    int v = (i < NNODE) ? deg[i] : 0;
    s[t] = v; __syncthreads();
    for (int o = 1; o < 256; o <<= 1) {
        int x = (t >= o) ? s[t - o] : 0;
        __syncthreads(); s[t] += x; __syncthreads();
    }
    if (i < NNODE) rowptr[i] = s[t] - v;
    if (t == 255) bsum[blockIdx.x] = s[t];
}
__global__ void egnn_scanF(int* rowptr, const int* bsum, int* cursor)
{
    __shared__ int red[256];
    int t = threadIdx.x, b = blockIdx.x;
    int acc = 0;
    for (int i = t; i < b; i += 256) acc += bsum[i];
    red[t] = acc; __syncthreads();
    for (int o = 128; o > 0; o >>= 1) {
        if (t < o) red[t] += red[t + o];
        __syncthreads();
    }
    int i = b * 256 + t;
    if (i < NNODE) cursor[i] = rowptr[i] + red[0];
}
// scatter: also pre-gather (row,col) and edge_attr into CSR-slot order,
// so the edge kernel has a single coalesced index-load level.
__global__ void egnn_scatter(const int* eidx, const float* ea, int* cursor,
                             int2* rc2, float* eap)
{
    int e = blockIdx.x * 256 + threadIdx.x;
    if (e < NEDGE) {
        int r = eidx[e], c = eidx[NEDGE + e];
        float a = ea[e];
        int p = atomicAdd(&cursor[r], 1);
        rc2[p] = make_int2(r, c);
        eap[p] = a;
    }
}

// ------------------------------------------------------------------ edge phase
__global__ __launch_bounds__(256, 4)
void egnn_edge(const short* hbf, const float* pos, const int2* rc2, const float* eap,
               const float* eb1, const float* eb2, const float* cb1,
               const float* cW2, const float* cb2,
               const short* eW1f, const short* eW2f, const short* cW1f,
               float* aggout, float* outpos)
{
    __shared__ __align__(16) short sX[EB * PX];   // unique h_rows -> bf16 m -> fp32 m (cols 0-63)
    __shared__ __align__(16) short sB[EB * PX];   // h_col -> silu(L1) -> fp32 m (cols 64-127)
    __shared__ int   rci[EB];
    __shared__ int   slotab[EB];   // per-edge unique-row slot
    __shared__ int   urow[EB];     // unique row ids
    __shared__ int   ucnt_s;
    __shared__ float rad[EB][4];
    __shared__ float ea_s[EB];
    __shared__ float part[EB][4];

    const int t  = threadIdx.x;
    const int e0 = blockIdx.x * EB;
    const int lane = t & 63;
    const int w    = t >> 6;
    const int l15  = lane & 15;
    const int q    = lane >> 4;
    const int ns   = w * 32;

    short8 bb[4][2];
    short8 a[4];
    f32x4 acc[2][4];
    float2 mreg2[4][4];

    // persisted wave-0 per-edge state (valid for t < EB)
    int   r_reg = 0, slot_reg = 0;
    float dxr = 0.f, dyr = 0.f, dzr = 0.f, rnr = 1.f;

    // hoisted biases / weights (off the inter-barrier dependent chain)
    const float bv1a = eb1[ns + l15];
    const float bv1b = eb1[ns + 16 + l15];
    const float bv2a = eb2[ns + l15];
    const float bv2b = eb2[ns + 16 + l15];
    const float bv3a = cb1[ns + l15];
    const float bv3b = cb1[ns + 16 + l15];
    const float cw0  = cW2[ns + l15];
    const float cw1  = cW2[ns + 16 + l15];
    const float cb2v = cb2[0];

    // preload GEMM1 B-frags for the COL phase first (logical k 128..255 -> kc+4)
#pragma unroll
    for (int kc = 0; kc < 4; ++kc)
#pragma unroll
        for (int nt = 0; nt < 2; ++nt)
            bb[kc][nt] = *(const short8*)&eW1f[(((w * 2 + nt) * 9 + kc + 4) * 64 + lane) * 8];

    // P1: stage h[col]->sB (rows are dedup-staged after B1)
    {
        int2 rcv[4];
#pragma unroll
        for (int it = 0; it < 4; ++it) rcv[it] = rc2[e0 + (t >> 4) + it * 16];
        const int c16 = t & 15;
#pragma unroll
        for (int it = 0; it < 4; ++it) {
            int e = (t >> 4) + it * 16;
            *(uint4*)&sB[e * PX + c16 * 8] = *(const uint4*)&hbf[(long)rcv[it].y * HID + c16 * 8];
        }
    }
    // P0: wave 0 builds index tables, run-slot table, geometry
    if (t < EB) {
        int2 rc = rc2[e0 + t];
        int r = rc.x, c = rc.y;
        r_reg = r;
        rci[t] = r;
        ea_s[t] = eap[e0 + t];
        float dx = pos[(long)r * 3 + 0] - pos[(long)c * 3 + 0];
        float dy = pos[(long)r * 3 + 1] - pos[(long)c * 3 + 1];
        float dz = pos[(long)r * 3 + 2] - pos[(long)c * 3 + 2];
        float rn = fmaxf(sqrtf(dx * dx + dy * dy + dz * dz), 1e-8f);
        dxr = dx; dyr = dy; dzr = dz; rnr = rn;
        rad[t][0] = dx; rad[t][1] = dy; rad[t][2] = dz; rad[t][3] = rn;
        int rprev = __shfl_up(r, 1);
        bool is_start = (t == 0) || (r != rprev);
        unsigned long long mask = __ballot(is_start);
        slot_reg = __popcll(mask << (63 - t)) - 1;   // rank of run containing edge t
        slotab[t] = slot_reg;
        if (is_start) urow[slot_reg] = r;
        if (t == 0) ucnt_s = __popcll(mask);
    }
    __syncthreads();   // B1: col staging + slot/urow tables visible

    // row staging: unique rows only (~5 typical, <=64 worst case)
    {
        const int c16 = t & 15;
        const int U = ucnt_s;
        for (int u = t >> 4; u < U; u += 16)
            *(uint4*)&sX[u * PX + c16 * 8] = *(const uint4*)&hbf[(long)urow[u] * HID + c16 * 8];
    }
    // per-thread slot lookup for A-frag indirection (broadcast reads)
    int sv[4];
#pragma unroll
    for (int mt = 0; mt < 4; ++mt) sv[mt] = slotab[mt * 16 + l15];

    // acc init
#pragma unroll
    for (int nt = 0; nt < 2; ++nt) {
        float bv = (nt == 0) ? bv1a : bv1b;
#pragma unroll
        for (int mt = 0; mt < 4; ++mt)
            for (int r = 0; r < 4; ++r) acc[nt][mt][r] = bv;
    }
    // GEMM1 phase A: col half (sB), logical k 128..255 — overlaps row-gather latency
#pragma unroll
    for (int kc = 0; kc < 4; ++kc) {
#pragma unroll
        for (int mt = 0; mt < 4; ++mt)
            a[mt] = *(const short8*)&sB[(mt * 16 + l15) * PX + kc * 32 + q * 8];
#pragma unroll
        for (int nt = 0; nt < 2; ++nt)
#pragma unroll
            for (int mt = 0; mt < 4; ++mt)
                acc[nt][mt] = __builtin_amdgcn_mfma_f32_16x16x32_bf16(a[mt], bb[kc][nt], acc[nt][mt], 0, 0, 0);
    }
    // preload row-half B-frags (logical k 0..127)
#pragma unroll
    for (int kc = 0; kc < 4; ++kc)
#pragma unroll
        for (int nt = 0; nt < 2; ++nt)
            bb[kc][nt] = *(const short8*)&eW1f[(((w * 2 + nt) * 9 + kc) * 64 + lane) * 8];
    __syncthreads();   // B2: dedup'd row staging visible

    // GEMM1 phase B: row half via slot indirection (same-slot lanes broadcast)
#pragma unroll
    for (int kc = 0; kc < 4; ++kc) {
#pragma unroll
        for (int mt = 0; mt < 4; ++mt)
            a[mt] = *(const short8*)&sX[sv[mt] * PX + kc * 32 + q * 8];
#pragma unroll
        for (int nt = 0; nt < 2; ++nt)
#pragma unroll
            for (int mt = 0; mt < 4; ++mt)
                acc[nt][mt] = __builtin_amdgcn_mfma_f32_16x16x32_bf16(a[mt], bb[kc][nt], acc[nt][mt], 0, 0, 0);
    }
    {   // kc8 tail: [rn, ea] columns
        short8 b8[2];
#pragma unroll
        for (int nt = 0; nt < 2; ++nt)
            b8[nt] = *(const short8*)&eW1f[(((w * 2 + nt) * 9 + 8) * 64 + lane) * 8];
#pragma unroll
        for (int mt = 0; mt < 4; ++mt) {
            int row = mt * 16 + l15;
            short8 a8;
#pragma unroll
            for (int j = 0; j < 8; ++j) a8[j] = 0;
            if (q == 0) {
                a8[0] = (short)f2bf(rad[row][3]);
                a8[1] = (short)f2bf(ea_s[row]);
            }
            a[mt] = a8;
        }
#pragma unroll
        for (int nt = 0; nt < 2; ++nt)
#pragma unroll
            for (int mt = 0; mt < 4; ++mt)
                acc[nt][mt] = __builtin_amdgcn_mfma_f32_16x16x32_bf16(a[mt], b8[nt], acc[nt][mt], 0, 0, 0);
    }
    // preload GEMM2 B-frags
#pragma unroll
    for (int kc = 0; kc < 4; ++kc)
#pragma unroll
        for (int nt = 0; nt < 2; ++nt)
            bb[kc][nt] = *(const short8*)&eW2f[(((w * 2 + nt) * 4 + kc) * 64 + lane) * 8];

    // GEMM1 epilogue: silu -> sB (all sB readers finished before B2; writes are per-wave disjoint)
#pragma unroll
    for (int mt = 0; mt < 4; ++mt)
#pragma unroll
        for (int r = 0; r < 4; ++r) {
            float2 v = silu2(acc[0][mt][r], acc[1][mt][r]);
            *(unsigned int*)&sB[(mt * 16 + q * 4 + r) * PX + ns + 2 * l15] = pkbf(v);
        }
    __syncthreads();   // B5

    // P5: GEMM2: sB @ eW2f -> silu = m (float2 regs + interleaved bf16 into sX)
#pragma unroll
    for (int nt = 0; nt < 2; ++nt) {
        float bv = (nt == 0) ? bv2a : bv2b;
#pragma unroll
        for (int mt = 0; mt < 4; ++mt)
            for (int r = 0; r < 4; ++r) acc[nt][mt][r] = bv;
    }
#pragma unroll
    for (int kc = 0; kc < 4; ++kc) {
#pragma unroll
        for (int mt = 0; mt < 4; ++mt)
            a[mt] = *(const short8*)&sB[(mt * 16 + l15) * PX + kc * 32 + q * 8];
#pragma unroll
        for (int nt = 0; nt < 2; ++nt)
#pragma unroll
            for (int mt = 0; mt < 4; ++mt)
                acc[nt][mt] = __builtin_amdgcn_mfma_f32_16x16x32_bf16(a[mt], bb[kc][nt], acc[nt][mt], 0, 0, 0);
    }
    // preload GEMM3 B-frags
#pragma unroll
    for (int kc = 0; kc < 4; ++kc)
#pragma unroll
        for (int nt = 0; nt < 2; ++nt)
            bb[kc][nt] = *(const short8*)&cW1f[(((w * 2 + nt) * 4 + kc) * 64 + lane) * 8];
#pragma unroll
    for (int mt = 0; mt < 4; ++mt)
#pragma unroll
        for (int r = 0; r < 4; ++r) {
            float2 v = silu2(acc[0][mt][r], acc[1][mt][r]);
            mreg2[mt][r] = v;
            *(unsigned int*)&sX[(mt * 16 + q * 4 + r) * PX + ns + 2 * l15] = pkbf(v);
        }
    __syncthreads();   // B6

    // P6: GEMM3: m @ cW1f -> silu -> dot(cW2) -> part
#pragma unroll
    for (int nt = 0; nt < 2; ++nt) {
        float bv = (nt == 0) ? bv3a : bv3b;
#pragma unroll
        for (int mt = 0; mt < 4; ++mt)
            for (int r = 0; r < 4; ++r) acc[nt][mt][r] = bv;
    }
#pragma unroll
    for (int kc = 0; kc < 4; ++kc) {
#pragma unroll
        for (int mt = 0; mt < 4; ++mt)
            a[mt] = *(const short8*)&sX[(mt * 16 + l15) * PX + kc * 32 + q * 8];
#pragma unroll
        for (int nt = 0; nt < 2; ++nt)
#pragma unroll
            for (int mt = 0; mt < 4; ++mt)
                acc[nt][mt] = __builtin_amdgcn_mfma_f32_16x16x32_bf16(a[mt], bb[kc][nt], acc[nt][mt], 0, 0, 0);
    }
    {
#pragma unroll
        for (int mt = 0; mt < 4; ++mt) {
            float p[4];
            for (int r = 0; r < 4; ++r) {
                float2 s = silu2(acc[0][mt][r], acc[1][mt][r]);
                p[r] = s.x * cw0 + s.y * cw1;
            }
            for (int mask = 1; mask < 16; mask <<= 1)
                for (int r = 0; r < 4; ++r) p[r] += __shfl_xor(p[r], mask);
            if (l15 == 0)
                for (int r = 0; r < 4; ++r) part[mt * 16 + q * 4 + r][w] = p[r];
        }
    }
    __syncthreads();   // B7

    // P7: fp32 m dump as float2 (waves 0,1 -> sX, waves 2,3 -> sB) + merged pos atomics
    {
        float2* dst = (w < 2) ? (float2*)sX : (float2*)sB;
        int cp = w * 16 + l15 - ((w < 2) ? 0 : 32);
#pragma unroll
        for (int mt = 0; mt < 4; ++mt)
#pragma unroll
            for (int r = 0; r < 4; ++r)
                dst[(mt * 16 + q * 4 + r) * 34 + cp] = mreg2[mt][r];
    }
    if (t < EB) {
        float cd  = part[t][0] + part[t][1] + part[t][2] + part[t][3] + cb2v;
        float inv = cd / rnr;
        float px = inv * dxr, py = inv * dyr, pz = inv * dzr;
        // segmented inclusive sum over same-row runs (wave 0 only)
        int sl = slot_reg;
#pragma unroll
        for (int off = 1; off < 64; off <<= 1) {
            float ux = __shfl_up(px, off);
            float uy = __shfl_up(py, off);
            float uz = __shfl_up(pz, off);
            int   su = __shfl_up(sl, off);
            if (t >= off && su == sl) { px += ux; py += uy; pz += uz; }
        }
        int snx = __shfl_down(sl, 1);
        if (t == 63 || snx != sl) {      // last edge of run -> one atomic triple per run
            atomicAdd(&outpos[(long)r_reg * 3 + 0], px);
            atomicAdd(&outpos[(long)r_reg * 3 + 1], py);
            atomicAdd(&outpos[(long)r_reg * 3 + 2], pz);
        }
    }
    __syncthreads();   // B8

    // P8: run-merged agg atomics: thread = (colquad, edge-eighth).
    // 8 uniform iterations, float4 LDS reads (conflict-free: 16 lanes x 16B contiguous).
    {
        int cq = t & 31;                  // colquad: phys cols 4cq..4cq+3
        int kq = t >> 5;                  // edge eighth
        const float4* srcf = (cq < 16) ? (const float4*)sX : (const float4*)sB;
        int cp = cq & 15;
        long j0 = 4 * cq;
        float s0 = 0.f, s1 = 0.f, s2 = 0.f, s3 = 0.f;
        int prev = rci[8 * kq];
#pragma unroll
        for (int e = 8 * kq; e < 8 * kq + 8; ++e) {
            int rr = rci[e];
            if (rr != prev) {
                atomicAdd(&aggout[(long)prev * HID + j0 + 0], s0);
                atomicAdd(&aggout[(long)prev * HID + j0 + 1], s1);
                atomicAdd(&aggout[(long)prev * HID + j0 + 2], s2);
                atomicAdd(&aggout[(long)prev * HID + j0 + 3], s3);
                s0 = s1 = s2 = s3 = 0.f; prev = rr;
            }
            float4 v = srcf[e * 17 + cp];
            s0 += v.x; s1 += v.y; s2 += v.z; s3 += v.w;
        }
        atomicAdd(&aggout[(long)prev * HID + j0 + 0], s0);
        atomicAdd(&aggout[(long)prev * HID + j0 + 1], s1);
        atomicAdd(&aggout[(long)prev * HID + j0 + 2], s2);
        atomicAdd(&aggout[(long)prev * HID + j0 + 3], s3);
    }
}

// ------------------------------------------------------------------ node phase (agg aliases out h-region)
// sB2 aliases sA (written only after all GEMM1 reads of sA) -> LDS 50.2KB -> 3 blocks/CU
__global__ __launch_bounds__(256, 3)
void egnn_node(const float* h, const short* hbf, const float* agg,
               const float* nb1, const float* nb2,
               const short* nW1f, const short* nW2f,
               float* out)
{
    __shared__ __align__(16) short sA[EB * PN];
    short* sB2 = sA;   // alias: epilogue writes gated by a barrier after GEMM1

    const int t  = threadIdx.x;
    const int n0 = blockIdx.x * EB;

    for (int i = t; i < EB * 16; i += 256) {
        int e = i >> 4, uu = i & 15;
        int nd = n0 + e; if (nd >= NNODE) nd = NNODE - 1;
        *(uint4*)&sA[e * PN + uu * 8] = *(const uint4*)&hbf[(long)nd * HID + uu * 8];
    }
    for (int i = t; i < EB * 32; i += 256) {
        int e = i >> 5, uu = i & 31;
        int nd = n0 + e; if (nd >= NNODE) nd = NNODE - 1;
        const float4 v = *(const float4*)&agg[(long)nd * HID + uu * 4];
        unsigned int h0 = pkbf(make_float2(v.x, v.y));
        unsigned int h1 = pkbf(make_float2(v.z, v.w));
        *(uint2*)&sA[e * PN + HID + uu * 4] = make_uint2(h0, h1);
        unsigned int l0 = pkbf(make_float2(v.x - bf2f((unsigned short)h0),
                                           v.y - bf2f((unsigned short)(h0 >> 16))));
        unsigned int l1 = pkbf(make_float2(v.z - bf2f((unsigned short)h1),
                                           v.w - bf2f((unsigned short)(h1 >> 16))));
        *(uint2*)&sA[e * PN + 2 * HID + uu * 4] = make_uint2(l0, l1);
    }
    __syncthreads();

    const int lane = t & 63;
    const int w    = t >> 6;
    const int l15  = lane & 15;
    const int q    = lane >> 4;
    const int ns   = w * 32;

    f32x4 acc[2][4];
    short8 a[4], b[2];

#pragma unroll
    for (int nt = 0; nt < 2; ++nt) {
        float bv = nb1[ns + nt * 16 + l15];
#pragma unroll
        for (int mt = 0; mt < 4; ++mt)
            for (int r = 0; r < 4; ++r) acc[nt][mt][r] = bv;
    }
    for (int kc = 0; kc < 12; ++kc) {
#pragma unroll
        for (int mt = 0; mt < 4; ++mt)
            a[mt] = *(const short8*)&sA[(mt * 16 + l15) * PN + kc * 32 + q * 8];
#pragma unroll
        for (int nt = 0; nt < 2; ++nt)
            b[nt] = *(const short8*)&nW1f[(((w * 2 + nt) * 12 + kc) * 64 + lane) * 8];
#pragma unroll
        for (int nt = 0; nt < 2; ++nt)
#pragma unroll
            for (int mt = 0; mt < 4; ++mt)
                acc[nt][mt] = __builtin_amdgcn_mfma_f32_16x16x32_bf16(a[mt], b[nt], acc[nt][mt], 0, 0, 0);
    }
    __syncthreads();   // all sA reads done -> safe to overwrite via sB2 alias
#pragma unroll
    for (int mt = 0; mt < 4; ++mt)
#pragma unroll
        for (int r = 0; r < 4; ++r) {
            float2 v = silu2(acc[0][mt][r], acc[1][mt][r]);
            *(unsigned int*)&sB2[(mt * 16 + q * 4 + r) * PX + ns + 2 * l15] = pkbf(v);
        }
    __syncthreads();

#pragma unroll
    for (int nt = 0; nt < 2; ++nt) {
        float bv = nb2[ns + nt * 16 + l15];
#pragma unroll
        for (int mt = 0; mt < 4; ++mt)
            for (int r = 0; r < 4; ++r) acc[nt][mt][r] = bv;
    }
    for (int kc = 0; kc < 4; ++kc) {
#pragma unroll
        for (int mt = 0; mt < 4; ++mt)
            a[mt] = *(const short8*)&sB2[(mt * 16 + l15) * PX + kc * 32 + q * 8];
#pragma unroll
        for (int nt = 0; nt < 2; ++nt)
            b[nt] = *(const short8*)&nW2f[(((w * 2 + nt) * 4 + kc) * 64 + lane) * 8];
#pragma unroll
        for (int nt = 0; nt < 2; ++nt)
#pragma unroll
            for (int mt = 0; mt < 4; ++mt)
                acc[nt][mt] = __builtin_amdgcn_mfma_f32_16x16x32_bf16(a[mt], b[nt], acc[nt][mt], 0, 0, 0);
    }
#pragma unroll
    for (int nt = 0; nt < 2; ++nt)
#pragma unroll
        for (int mt = 0; mt < 4; ++mt)
            for (int r = 0; r < 4; ++r) {
                int m  = mt * 16 + q * 4 + r;
                int nd = n0 + m;
                if (nd < NNODE) {
                    int n = ns + nt * 16 + l15;
                    out[(long)nd * HID + n] = h[(long)nd * HID + n] + acc[nt][mt][r];
                }
            }
}

// ------------------------------------------------------------------ launch
extern "C" void kernel_launch(void* const* d_in, const int* in_sizes, int n_in,
                              void* d_out, int out_size, void* d_ws, size_t ws_size,
                              hipStream_t stream)
{
    const float* h    = (const float*)d_in[0];
    const float* pos  = (const float*)d_in[1];
    const float* ea   = (const float*)d_in[2];
    const int*   eidx = (const int*)d_in[3];
    const float* eW1  = (const float*)d_in[4];
    const float* eb1  = (const float*)d_in[5];
    const float* eW2  = (const float*)d_in[6];
    const float* eb2  = (const float*)d_in[7];
    const float* nW1  = (const float*)d_in[8];
    const float* nb1  = (const float*)d_in[9];
    const float* nW2  = (const float*)d_in[10];
    const float* nb2  = (const float*)d_in[11];
    const float* cW1  = (const float*)d_in[12];
    const float* cb1  = (const float*)d_in[13];
    const float* cW2  = (const float*)d_in[14];
    const float* cb2  = (const float*)d_in[15];

    float* out    = (float*)d_out;
    float* outpos = out + (long)NNODE * HID;

    char* ws = (char*)d_ws;
    short* wsw    = (short*)ws;
    short* hbf    = (short*)(ws + WS_HBF);
    int*   deg    = (int*)(ws + WS_DEG);
    int*   rowptr = (int*)(ws + WS_ROW);
    int*   cursor = (int*)(ws + WS_CUR);
    int*   bsum   = (int*)(ws + WS_BSUM);
    int2*  rc2    = (int2*)(ws + WS_RC2);
    float* eap    = (float*)(ws + WS_EAP);

    const short* eW1f = wsw;
    const short* eW2f = wsw + 4608 * 8;
    const short* cW1f = wsw + 6656 * 8;
    const short* nW1f = wsw + 8704 * 8;
    const short* nW2f = wsw + 14848 * 8;

    egnn_prep<<<(2616896 + 255) / 256, 256, 0, stream>>>(
        eW1, eW2, cW1, nW1, nW2, h, pos, wsw, hbf, deg, out);
    egnn_hist<<<(NEDGE / 4 + 255) / 256, 256, 0, stream>>>(eidx, deg);
    egnn_scan1<<<196, 256, 0, stream>>>(deg, rowptr, bsum);
    egnn_scanF<<<196, 256, 0, stream>>>(rowptr, bsum, cursor);
    egnn_scatter<<<(NEDGE + 255) / 256, 256, 0, stream>>>(eidx, ea, cursor, rc2, eap);
    egnn_edge<<<NEDGE / EB, 256, 0, stream>>>(hbf, pos, rc2, eap,
                                              eb1, eb2, cb1, cW2, cb2,
                                              eW1f, eW2f, cW1f, out, outpos);
    egnn_node<<<(NNODE + EB - 1) / EB, 256, 0, stream>>>(h, hbf, out, nb1, nb2,
                                                         nW1f, nW2f, out);
}

// Round 7
// 411.323 us; speedup vs baseline: 1.3866x; 1.3866x over previous
//
#include <hip/hip_runtime.h>
#include <hip/hip_bf16.h>
#include <math.h>

#define HID   128
#define NNODE 50000
#define NEDGE 800000
#define EB    64
#define PX    136   // edge/intermediate pitch (shorts) = 68 dwords = 34 float2
#define PN    392   // node featA pitch (shorts): [h | agg_hi | agg_lo]

typedef __attribute__((ext_vector_type(8))) short short8;
typedef __attribute__((ext_vector_type(4))) float f32x4;

__device__ __forceinline__ float2 silu2(float x, float y) {
    return make_float2(x * __builtin_amdgcn_rcpf(1.0f + __expf(-x)),
                       y * __builtin_amdgcn_rcpf(1.0f + __expf(-y)));
}
__device__ __forceinline__ unsigned int pkbf(float2 v) {   // packed RNE f32x2 -> bf16x2
    __hip_bfloat162 b2 = __float22bfloat162_rn(v);
    return *(unsigned int*)&b2;
}
__device__ __forceinline__ unsigned short f2bf(float f) {  // scalar RNE
    unsigned int u = __float_as_uint(f);
    u += 0x7FFFu + ((u >> 16) & 1u);
    return (unsigned short)(u >> 16);
}
__device__ __forceinline__ float bf2f(unsigned short s) {
    return __uint_as_float(((unsigned int)s) << 16);
}
// physical col p (in a 128-wide interleaved buffer) -> logical col
__device__ __forceinline__ int permk(int p) {
    return (p & ~31) | ((p & 31) >> 1) | ((p & 1) << 4);
}

// ws layout (bytes)
#define WS_HBF  270336
#define WS_DEG  13070336
#define WS_ROW  13270336
#define WS_CUR  13470336
#define WS_BSUM 13670336
#define WS_RC2  13671360
#define WS_EAP  20071360

// ------------------------------------------------------------------ prep
__global__ void egnn_prep(const float* eW1, const float* eW2, const float* cW1,
                          const float* nW1, const float* nW2, const float* h,
                          const float* pos,
                          short* wsw, short* hbf, int* deg, float* out)
{
    int g = blockIdx.x * 256 + threadIdx.x;
    if (g < 16896) {
        const float* src; short* dst; int u, Kr, KC, mode;
        if (g < 4608)       { src = eW1; dst = wsw;            u = g;         Kr = 258; KC = 9;  mode = 0; }
        else if (g < 6656)  { src = eW2; dst = wsw + 4608*8;   u = g - 4608;  Kr = 128; KC = 4;  mode = 1; }
        else if (g < 8704)  { src = cW1; dst = wsw + 6656*8;   u = g - 6656;  Kr = 128; KC = 4;  mode = 1; }
        else if (g < 14848) { src = nW1; dst = wsw + 8704*8;   u = g - 8704;  Kr = 384; KC = 12; mode = 2; }
        else                { src = nW2; dst = wsw + 14848*8;  u = g - 14848; Kr = 128; KC = 4;  mode = 1; }
        int nt   = u / (KC * 64);
        int rem  = u % (KC * 64);
        int kc   = rem >> 6;
        int lane = rem & 63;
        int n    = nt * 16 + (lane & 15);
        int kb   = kc * 32 + ((lane >> 4) & 3) * 8;
        short8 o;
#pragma unroll
        for (int j = 0; j < 8; ++j) {
            int k = kb + j;
            int ks;
            if (mode == 0)      ks = k;
            else if (mode == 1) ks = permk(k);
            else {              // nW1: h natural, agg hi/lo permuted (lo reuses same rows)
                if (k < 128)      ks = k;
                else if (k < 256) ks = 128 + permk(k - 128);
                else              ks = 128 + permk(k - 256);
            }
            float v = (k < Kr) ? src[(long)ks * HID + n] : 0.0f;
            o[j] = (short)f2bf(v);
        }
        *(short8*)&dst[(long)u * 8] = o;
    } else if (g < 816896) {                       // h -> bf16
        long i = (long)(g - 16896) * 8;
        const float4 v0 = *(const float4*)&h[i];
        const float4 v1 = *(const float4*)&h[i + 4];
        uint4 o;
        o.x = pkbf(make_float2(v0.x, v0.y));
        o.y = pkbf(make_float2(v0.z, v0.w));
        o.z = pkbf(make_float2(v1.x, v1.y));
        o.w = pkbf(make_float2(v1.z, v1.w));
        *(uint4*)&hbf[i] = o;
    } else if (g < 2416896) {                      // zero agg region
        long i = (long)(g - 816896);
        ((float4*)out)[i] = make_float4(0.f, 0.f, 0.f, 0.f);
    } else if (g < 2566896) {                      // pos -> outpos
        int i = g - 2416896;
        out[(long)NNODE * HID + i] = pos[i];
    } else if (g < 2616896) {                      // zero deg
        int i = g - 2566896;
        deg[i] = 0;
    }
}

// ------------------------------------------------------------------ CSR build
__global__ void egnn_hist(const int* eidx, int* deg)
{
    int i = blockIdx.x * 256 + threadIdx.x;
    if (i < NEDGE / 4) {
        int4 v = ((const int4*)eidx)[i];
        atomicAdd(&deg[v.x], 1); atomicAdd(&deg[v.y], 1);
        atomicAdd(&deg[v.z], 1); atomicAdd(&deg[v.w], 1);
    }
}
__global__ void egnn_scan1(const int* deg, int* rowptr, int* bsum)
{
    __shared__ int s[256];
    int t = threadIdx.x, i = blockIdx.x * 256 + t;
    int v = (i < NNODE) ? deg[i] : 0;
    s[t] = v; __syncthreads();
    for (int o = 1; o < 256; o <<= 1) {
        int x = (t >= o) ? s[t - o] : 0;
        __syncthreads(); s[t] += x; __syncthreads();
    }
    if (i < NNODE) rowptr[i] = s[t] - v;
    if (t == 255) bsum[blockIdx.x] = s[t];
}
__global__ void egnn_scanF(int* rowptr, const int* bsum, int* cursor)
{
    __shared__ int red[256];
    int t = threadIdx.x, b = blockIdx.x;
    int acc = 0;
    for (int i = t; i < b; i += 256) acc += bsum[i];
    red[t] = acc; __syncthreads();
    for (int o = 128; o > 0; o >>= 1) {
        if (t < o) red[t] += red[t + o];
        __syncthreads();
    }
    int i = b * 256 + t;
    if (i < NNODE) cursor[i] = rowptr[i] + red[0];
}
// scatter: also pre-gather (row,col) and edge_attr into CSR-slot order,
// so the edge kernel has a single coalesced index-load level.
__global__ void egnn_scatter(const int* eidx, const float* ea, int* cursor,
                             int2* rc2, float* eap)
{
    int e = blockIdx.x * 256 + threadIdx.x;
    if (e < NEDGE) {
        int r = eidx[e], c = eidx[NEDGE + e];
        float a = ea[e];
        int p = atomicAdd(&cursor[r], 1);
        rc2[p] = make_int2(r, c);
        eap[p] = a;
    }
}

// ------------------------------------------------------------------ edge phase
__global__ __launch_bounds__(256, 4)
void egnn_edge(const short* hbf, const float* pos, const int2* rc2, const float* eap,
               const float* eb1, const float* eb2, const float* cb1,
               const float* cW2, const float* cb2,
               const short* eW1f, const short* eW2f, const short* cW1f,
               float* aggout, float* outpos)
{
    __shared__ __align__(16) short sX[EB * PX];   // unique h_rows -> bf16 m -> fp32 m (cols 0-63)
    __shared__ __align__(16) short sB[EB * PX];   // h_col -> silu(L1) -> fp32 m (cols 64-127)
    __shared__ int   rci[EB];
    __shared__ int   slotab[EB];   // per-edge unique-row slot
    __shared__ int   urow[EB];     // unique row ids
    __shared__ int   ucnt_s;
    __shared__ float rad[EB][4];
    __shared__ float ea_s[EB];
    __shared__ float part[EB][4];

    const int t  = threadIdx.x;
    const int e0 = blockIdx.x * EB;
    const int lane = t & 63;
    const int w    = t >> 6;
    const int l15  = lane & 15;
    const int q    = lane >> 4;
    const int ns   = w * 32;

    short8 bb[4][2];
    short8 a[4];
    f32x4 acc[2][4];
    float2 mreg2[4][4];

    // persisted wave-0 per-edge state (valid for t < EB)
    int   r_reg = 0, slot_reg = 0;
    float dxr = 0.f, dyr = 0.f, dzr = 0.f, rnr = 1.f;

    // hoisted biases / weights (off the inter-barrier dependent chain)
    const float bv1a = eb1[ns + l15];
    const float bv1b = eb1[ns + 16 + l15];
    const float bv2a = eb2[ns + l15];
    const float bv2b = eb2[ns + 16 + l15];
    const float bv3a = cb1[ns + l15];
    const float bv3b = cb1[ns + 16 + l15];
    const float cw0  = cW2[ns + l15];
    const float cw1  = cW2[ns + 16 + l15];
    const float cb2v = cb2[0];

    // preload GEMM1 B-frags for the COL phase first (logical k 128..255 -> kc+4)
#pragma unroll
    for (int kc = 0; kc < 4; ++kc)
#pragma unroll
        for (int nt = 0; nt < 2; ++nt)
            bb[kc][nt] = *(const short8*)&eW1f[(((w * 2 + nt) * 9 + kc + 4) * 64 + lane) * 8];

    // P1: stage h[col]->sB (rows are dedup-staged after B1)
    {
        int2 rcv[4];
#pragma unroll
        for (int it = 0; it < 4; ++it) rcv[it] = rc2[e0 + (t >> 4) + it * 16];
        const int c16 = t & 15;
#pragma unroll
        for (int it = 0; it < 4; ++it) {
            int e = (t >> 4) + it * 16;
            *(uint4*)&sB[e * PX + c16 * 8] = *(const uint4*)&hbf[(long)rcv[it].y * HID + c16 * 8];
        }
    }
    // P0: wave 0 builds index tables, run-slot table, geometry
    if (t < EB) {
        int2 rc = rc2[e0 + t];
        int r = rc.x, c = rc.y;
        r_reg = r;
        rci[t] = r;
        ea_s[t] = eap[e0 + t];
        float dx = pos[(long)r * 3 + 0] - pos[(long)c * 3 + 0];
        float dy = pos[(long)r * 3 + 1] - pos[(long)c * 3 + 1];
        float dz = pos[(long)r * 3 + 2] - pos[(long)c * 3 + 2];
        float rn = fmaxf(sqrtf(dx * dx + dy * dy + dz * dz), 1e-8f);
        dxr = dx; dyr = dy; dzr = dz; rnr = rn;
        rad[t][0] = dx; rad[t][1] = dy; rad[t][2] = dz; rad[t][3] = rn;
        int rprev = __shfl_up(r, 1);
        bool is_start = (t == 0) || (r != rprev);
        unsigned long long mask = __ballot(is_start);
        slot_reg = __popcll(mask << (63 - t)) - 1;   // rank of run containing edge t
        slotab[t] = slot_reg;
        if (is_start) urow[slot_reg] = r;
        if (t == 0) ucnt_s = __popcll(mask);
    }
    __syncthreads();   // B1: col staging + slot/urow tables visible

    // row staging: unique rows only (~5 typical, <=64 worst case)
    {
        const int c16 = t & 15;
        const int U = ucnt_s;
        for (int u = t >> 4; u < U; u += 16)
            *(uint4*)&sX[u * PX + c16 * 8] = *(const uint4*)&hbf[(long)urow[u] * HID + c16 * 8];
    }
    // per-thread slot lookup for A-frag indirection (broadcast reads)
    int sv[4];
#pragma unroll
    for (int mt = 0; mt < 4; ++mt) sv[mt] = slotab[mt * 16 + l15];

    // acc init
#pragma unroll
    for (int nt = 0; nt < 2; ++nt) {
        float bv = (nt == 0) ? bv1a : bv1b;
#pragma unroll
        for (int mt = 0; mt < 4; ++mt)
            for (int r = 0; r < 4; ++r) acc[nt][mt][r] = bv;
    }
    // GEMM1 phase A: col half (sB), logical k 128..255 — overlaps row-gather latency
#pragma unroll
    for (int kc = 0; kc < 4; ++kc) {
#pragma unroll
        for (int mt = 0; mt < 4; ++mt)
            a[mt] = *(const short8*)&sB[(mt * 16 + l15) * PX + kc * 32 + q * 8];
#pragma unroll
        for (int nt = 0; nt < 2; ++nt)
#pragma unroll
            for (int mt = 0; mt < 4; ++mt)
                acc[nt][mt] = __builtin_amdgcn_mfma_f32_16x16x32_bf16(a[mt], bb[kc][nt], acc[nt][mt], 0, 0, 0);
    }
    // preload row-half B-frags (logical k 0..127)
#pragma unroll
    for (int kc = 0; kc < 4; ++kc)
#pragma unroll
        for (int nt = 0; nt < 2; ++nt)
            bb[kc][nt] = *(const short8*)&eW1f[(((w * 2 + nt) * 9 + kc) * 64 + lane) * 8];
    __syncthreads();   // B2: dedup'd row staging visible

    // GEMM1 phase B: row half via slot indirection (same-slot lanes broadcast)
#pragma unroll
    for (int kc = 0; kc < 4; ++kc) {
#pragma unroll
        for (int mt = 0; mt < 4; ++mt)
            a[mt] = *(const short8*)&sX[sv[mt] * PX + kc * 32 + q * 8];
#pragma unroll
        for (int nt = 0; nt < 2; ++nt)
#pragma unroll
            for (int mt = 0; mt < 4; ++mt)
                acc[nt][mt] = __builtin_amdgcn_mfma_f32_16x16x32_bf16(a[mt], bb[kc][nt], acc[nt][mt], 0, 0, 0);
    }
    {   // kc8 tail: [rn, ea] columns
        short8 b8[2];
#pragma unroll
        for (int nt = 0; nt < 2; ++nt)
            b8[nt] = *(const short8*)&eW1f[(((w * 2 + nt) * 9 + 8) * 64 + lane) * 8];
#pragma unroll
        for (int mt = 0; mt < 4; ++mt) {
            int row = mt * 16 + l15;
            short8 a8;
#pragma unroll
            for (int j = 0; j < 8; ++j) a8[j] = 0;
            if (q == 0) {
                a8[0] = (short)f2bf(rad[row][3]);
                a8[1] = (short)f2bf(ea_s[row]);
            }
            a[mt] = a8;
        }
#pragma unroll
        for (int nt = 0; nt < 2; ++nt)
#pragma unroll
            for (int mt = 0; mt < 4; ++mt)
                acc[nt][mt] = __builtin_amdgcn_mfma_f32_16x16x32_bf16(a[mt], b8[nt], acc[nt][mt], 0, 0, 0);
    }
    // preload GEMM2 B-frags
#pragma unroll
    for (int kc = 0; kc < 4; ++kc)
#pragma unroll
        for (int nt = 0; nt < 2; ++nt)
            bb[kc][nt] = *(const short8*)&eW2f[(((w * 2 + nt) * 4 + kc) * 64 + lane) * 8];

    // GEMM1 epilogue: silu -> sB (all sB readers finished before B2; writes are per-wave disjoint)
#pragma unroll
    for (int mt = 0; mt < 4; ++mt)
#pragma unroll
        for (int r = 0; r < 4; ++r) {
            float2 v = silu2(acc[0][mt][r], acc[1][mt][r]);
            *(unsigned int*)&sB[(mt * 16 + q * 4 + r) * PX + ns + 2 * l15] = pkbf(v);
        }
    __syncthreads();   // B5

    // P5: GEMM2: sB @ eW2f -> silu = m (float2 regs + interleaved bf16 into sX)
#pragma unroll
    for (int nt = 0; nt < 2; ++nt) {
        float bv = (nt == 0) ? bv2a : bv2b;
#pragma unroll
        for (int mt = 0; mt < 4; ++mt)
            for (int r = 0; r < 4; ++r) acc[nt][mt][r] = bv;
    }
#pragma unroll
    for (int kc = 0; kc < 4; ++kc) {
#pragma unroll
        for (int mt = 0; mt < 4; ++mt)
            a[mt] = *(const short8*)&sB[(mt * 16 + l15) * PX + kc * 32 + q * 8];
#pragma unroll
        for (int nt = 0; nt < 2; ++nt)
#pragma unroll
            for (int mt = 0; mt < 4; ++mt)
                acc[nt][mt] = __builtin_amdgcn_mfma_f32_16x16x32_bf16(a[mt], bb[kc][nt], acc[nt][mt], 0, 0, 0);
    }
    // preload GEMM3 B-frags
#pragma unroll
    for (int kc = 0; kc < 4; ++kc)
#pragma unroll
        for (int nt = 0; nt < 2; ++nt)
            bb[kc][nt] = *(const short8*)&cW1f[(((w * 2 + nt) * 4 + kc) * 64 + lane) * 8];
#pragma unroll
    for (int mt = 0; mt < 4; ++mt)
#pragma unroll
        for (int r = 0; r < 4; ++r) {
            float2 v = silu2(acc[0][mt][r], acc[1][mt][r]);
            mreg2[mt][r] = v;
            *(unsigned int*)&sX[(mt * 16 + q * 4 + r) * PX + ns + 2 * l15] = pkbf(v);
        }
    __syncthreads();   // B6

    // P6: GEMM3: m @ cW1f -> silu -> dot(cW2) -> part
#pragma unroll
    for (int nt = 0; nt < 2; ++nt) {
        float bv = (nt == 0) ? bv3a : bv3b;
#pragma unroll
        for (int mt = 0; mt < 4; ++mt)
            for (int r = 0; r < 4; ++r) acc[nt][mt][r] = bv;
    }
#pragma unroll
    for (int kc = 0; kc < 4; ++kc) {
#pragma unroll
        for (int mt = 0; mt < 4; ++mt)
            a[mt] = *(const short8*)&sX[(mt * 16 + l15) * PX + kc * 32 + q * 8];
#pragma unroll
        for (int nt = 0; nt < 2; ++nt)
#pragma unroll
            for (int mt = 0; mt < 4; ++mt)
                acc[nt][mt] = __builtin_amdgcn_mfma_f32_16x16x32_bf16(a[mt], bb[kc][nt], acc[nt][mt], 0, 0, 0);
    }
    {
#pragma unroll
        for (int mt = 0; mt < 4; ++mt) {
            float p[4];
            for (int r = 0; r < 4; ++r) {
                float2 s = silu2(acc[0][mt][r], acc[1][mt][r]);
                p[r] = s.x * cw0 + s.y * cw1;
            }
            for (int mask = 1; mask < 16; mask <<= 1)
                for (int r = 0; r < 4; ++r) p[r] += __shfl_xor(p[r], mask);
            if (l15 == 0)
                for (int r = 0; r < 4; ++r) part[mt * 16 + q * 4 + r][w] = p[r];
        }
    }
    __syncthreads();   // B7

    // P7: fp32 m dump as float2 (waves 0,1 -> sX, waves 2,3 -> sB) + merged pos atomics
    {
        float2* dst = (w < 2) ? (float2*)sX : (float2*)sB;
        int cp = w * 16 + l15 - ((w < 2) ? 0 : 32);
#pragma unroll
        for (int mt = 0; mt < 4; ++mt)
#pragma unroll
            for (int r = 0; r < 4; ++r)
                dst[(mt * 16 + q * 4 + r) * 34 + cp] = mreg2[mt][r];
    }
    if (t < EB) {
        float cd  = part[t][0] + part[t][1] + part[t][2] + part[t][3] + cb2v;
        float inv = cd / rnr;
        float px = inv * dxr, py = inv * dyr, pz = inv * dzr;
        // segmented inclusive sum over same-row runs (wave 0 only)
        int sl = slot_reg;
#pragma unroll
        for (int off = 1; off < 64; off <<= 1) {
            float ux = __shfl_up(px, off);
            float uy = __shfl_up(py, off);
            float uz = __shfl_up(pz, off);
            int   su = __shfl_up(sl, off);
            if (t >= off && su == sl) { px += ux; py += uy; pz += uz; }
        }
        int snx = __shfl_down(sl, 1);
        if (t == 63 || snx != sl) {      // last edge of run -> one atomic triple per run
            atomicAdd(&outpos[(long)r_reg * 3 + 0], px);
            atomicAdd(&outpos[(long)r_reg * 3 + 1], py);
            atomicAdd(&outpos[(long)r_reg * 3 + 2], pz);
        }
    }
    __syncthreads();   // B8

    // P8: run-merged agg atomics: thread = (colpair, edge-quarter), kq = t>>6 is
    // WAVE-UNIFORM (critical: uniform boundary branches, coherent flush atomics).
    {
        int cpg = t & 63;                 // colpair: phys cols (2*cpg, 2*cpg+1)
        int kq  = t >> 6;                 // edge quarter (uniform across the wave)
        const float2* srcf = (cpg < 32) ? (const float2*)sX : (const float2*)sB;
        int cp = cpg & 31;
        long j0 = 2 * cpg;
        float s0 = 0.0f, s1 = 0.0f;
        int prev = rci[16 * kq];
        for (int e = 16 * kq; e < 16 * kq + 16; ++e) {
            int rr = rci[e];
            if (rr != prev) {
                atomicAdd(&aggout[(long)prev * HID + j0], s0);
                atomicAdd(&aggout[(long)prev * HID + j0 + 1], s1);
                s0 = 0.0f; s1 = 0.0f; prev = rr;
            }
            float2 v = srcf[e * 34 + cp];
            s0 += v.x; s1 += v.y;
        }
        atomicAdd(&aggout[(long)prev * HID + j0], s0);
        atomicAdd(&aggout[(long)prev * HID + j0 + 1], s1);
    }
}

// ------------------------------------------------------------------ node phase (agg aliases out h-region)
// sB2 aliases sA (written only after all GEMM1 reads of sA) -> LDS 50.2KB -> 3 blocks/CU
__global__ __launch_bounds__(256, 3)
void egnn_node(const float* h, const short* hbf, const float* agg,
               const float* nb1, const float* nb2,
               const short* nW1f, const short* nW2f,
               float* out)
{
    __shared__ __align__(16) short sA[EB * PN];
    short* sB2 = sA;   // alias: epilogue writes gated by a barrier after GEMM1

    const int t  = threadIdx.x;
    const int n0 = blockIdx.x * EB;

    for (int i = t; i < EB * 16; i += 256) {
        int e = i >> 4, uu = i & 15;
        int nd = n0 + e; if (nd >= NNODE) nd = NNODE - 1;
        *(uint4*)&sA[e * PN + uu * 8] = *(const uint4*)&hbf[(long)nd * HID + uu * 8];
    }
    for (int i = t; i < EB * 32; i += 256) {
        int e = i >> 5, uu = i & 31;
        int nd = n0 + e; if (nd >= NNODE) nd = NNODE - 1;
        const float4 v = *(const float4*)&agg[(long)nd * HID + uu * 4];
        unsigned int h0 = pkbf(make_float2(v.x, v.y));
        unsigned int h1 = pkbf(make_float2(v.z, v.w));
        *(uint2*)&sA[e * PN + HID + uu * 4] = make_uint2(h0, h1);
        unsigned int l0 = pkbf(make_float2(v.x - bf2f((unsigned short)h0),
                                           v.y - bf2f((unsigned short)(h0 >> 16))));
        unsigned int l1 = pkbf(make_float2(v.z - bf2f((unsigned short)h1),
                                           v.w - bf2f((unsigned short)(h1 >> 16))));
        *(uint2*)&sA[e * PN + 2 * HID + uu * 4] = make_uint2(l0, l1);
    }
    __syncthreads();

    const int lane = t & 63;
    const int w    = t >> 6;
    const int l15  = lane & 15;
    const int q    = lane >> 4;
    const int ns   = w * 32;

    f32x4 acc[2][4];
    short8 a[4], b[2];

#pragma unroll
    for (int nt = 0; nt < 2; ++nt) {
        float bv = nb1[ns + nt * 16 + l15];
#pragma unroll
        for (int mt = 0; mt < 4; ++mt)
            for (int r = 0; r < 4; ++r) acc[nt][mt][r] = bv;
    }
    for (int kc = 0; kc < 12; ++kc) {
#pragma unroll
        for (int mt = 0; mt < 4; ++mt)
            a[mt] = *(const short8*)&sA[(mt * 16 + l15) * PN + kc * 32 + q * 8];
#pragma unroll
        for (int nt = 0; nt < 2; ++nt)
            b[nt] = *(const short8*)&nW1f[(((w * 2 + nt) * 12 + kc) * 64 + lane) * 8];
#pragma unroll
        for (int nt = 0; nt < 2; ++nt)
#pragma unroll
            for (int mt = 0; mt < 4; ++mt)
                acc[nt][mt] = __builtin_amdgcn_mfma_f32_16x16x32_bf16(a[mt], b[nt], acc[nt][mt], 0, 0, 0);
    }
    __syncthreads();   // all sA reads done -> safe to overwrite via sB2 alias
#pragma unroll
    for (int mt = 0; mt < 4; ++mt)
#pragma unroll
        for (int r = 0; r < 4; ++r) {
            float2 v = silu2(acc[0][mt][r], acc[1][mt][r]);
            *(unsigned int*)&sB2[(mt * 16 + q * 4 + r) * PX + ns + 2 * l15] = pkbf(v);
        }
    __syncthreads();

#pragma unroll
    for (int nt = 0; nt < 2; ++nt) {
        float bv = nb2[ns + nt * 16 + l15];
#pragma unroll
        for (int mt = 0; mt < 4; ++mt)
            for (int r = 0; r < 4; ++r) acc[nt][mt][r] = bv;
    }
    for (int kc = 0; kc < 4; ++kc) {
#pragma unroll
        for (int mt = 0; mt < 4; ++mt)
            a[mt] = *(const short8*)&sB2[(mt * 16 + l15) * PX + kc * 32 + q * 8];
#pragma unroll
        for (int nt = 0; nt < 2; ++nt)
            b[nt] = *(const short8*)&nW2f[(((w * 2 + nt) * 4 + kc) * 64 + lane) * 8];
#pragma unroll
        for (int nt = 0; nt < 2; ++nt)
#pragma unroll
            for (int mt = 0; mt < 4; ++mt)
                acc[nt][mt] = __builtin_amdgcn_mfma_f32_16x16x32_bf16(a[mt], b[nt], acc[nt][mt], 0, 0, 0);
    }
#pragma unroll
    for (int nt = 0; nt < 2; ++nt)
#pragma unroll
        for (int mt = 0; mt < 4; ++mt)
            for (int r = 0; r < 4; ++r) {
                int m  = mt * 16 + q * 4 + r;
                int nd = n0 + m;
                if (nd < NNODE) {
                    int n = ns + nt * 16 + l15;
                    out[(long)nd * HID + n] = h[(long)nd * HID + n] + acc[nt][mt][r];
                }
            }
}

// ------------------------------------------------------------------ launch
extern "C" void kernel_launch(void* const* d_in, const int* in_sizes, int n_in,
                              void* d_out, int out_size, void* d_ws, size_t ws_size,
                              hipStream_t stream)
{
    const float* h    = (const float*)d_in[0];
    const float* pos  = (const float*)d_in[1];
    const float* ea   = (const float*)d_in[2];
    const int*   eidx = (const int*)d_in[3];
    const float* eW1  = (const float*)d_in[4];
    const float* eb1  = (const float*)d_in[5];
    const float* eW2  = (const float*)d_in[6];
    const float* eb2  = (const float*)d_in[7];
    const float* nW1  = (const float*)d_in[8];
    const float* nb1  = (const float*)d_in[9];
    const float* nW2  = (const float*)d_in[10];
    const float* nb2  = (const float*)d_in[11];
    const float* cW1  = (const float*)d_in[12];
    const float* cb1  = (const float*)d_in[13];
    const float* cW2  = (const float*)d_in[14];
    const float* cb2  = (const float*)d_in[15];

    float* out    = (float*)d_out;
    float* outpos = out + (long)NNODE * HID;

    char* ws = (char*)d_ws;
    short* wsw    = (short*)ws;
    short* hbf    = (short*)(ws + WS_HBF);
    int*   deg    = (int*)(ws + WS_DEG);
    int*   rowptr = (int*)(ws + WS_ROW);
    int*   cursor = (int*)(ws + WS_CUR);
    int*   bsum   = (int*)(ws + WS_BSUM);
    int2*  rc2    = (int2*)(ws + WS_RC2);
    float* eap    = (float*)(ws + WS_EAP);

    const short* eW1f = wsw;
    const short* eW2f = wsw + 4608 * 8;
    const short* cW1f = wsw + 6656 * 8;
    const short* nW1f = wsw + 8704 * 8;
    const short* nW2f = wsw + 14848 * 8;

    egnn_prep<<<(2616896 + 255) / 256, 256, 0, stream>>>(
        eW1, eW2, cW1, nW1, nW2, h, pos, wsw, hbf, deg, out);
    egnn_hist<<<(NEDGE / 4 + 255) / 256, 256, 0, stream>>>(eidx, deg);
    egnn_scan1<<<196, 256, 0, stream>>>(deg, rowptr, bsum);
    egnn_scanF<<<196, 256, 0, stream>>>(rowptr, bsum, cursor);
    egnn_scatter<<<(NEDGE + 255) / 256, 256, 0, stream>>>(eidx, ea, cursor, rc2, eap);
    egnn_edge<<<NEDGE / EB, 256, 0, stream>>>(hbf, pos, rc2, eap,
                                              eb1, eb2, cb1, cW2, cb2,
                                              eW1f, eW2f, cW1f, out, outpos);
    egnn_node<<<(NNODE + EB - 1) / EB, 256, 0, stream>>>(h, hbf, out, nb1, nb2,
                                                         nW1f, nW2f, out);
}

// Round 8
// 408.473 us; speedup vs baseline: 1.3963x; 1.0070x over previous
//
#include <hip/hip_runtime.h>
#include <hip/hip_bf16.h>
#include <math.h>

#define HID   128
#define NNODE 50000
#define NEDGE 800000
#define EB    64
#define PX    136   // edge/intermediate pitch (shorts) = 68 dwords = 34 float2
#define PN    392   // node featA pitch (shorts): [h | agg_hi | agg_lo]

typedef __attribute__((ext_vector_type(8))) short short8;
typedef __attribute__((ext_vector_type(4))) float f32x4;

__device__ __forceinline__ float2 silu2(float x, float y) {
    return make_float2(x * __builtin_amdgcn_rcpf(1.0f + __expf(-x)),
                       y * __builtin_amdgcn_rcpf(1.0f + __expf(-y)));
}
__device__ __forceinline__ unsigned int pkbf(float2 v) {   // packed RNE f32x2 -> bf16x2
    __hip_bfloat162 b2 = __float22bfloat162_rn(v);
    return *(unsigned int*)&b2;
}
__device__ __forceinline__ unsigned short f2bf(float f) {  // scalar RNE
    unsigned int u = __float_as_uint(f);
    u += 0x7FFFu + ((u >> 16) & 1u);
    return (unsigned short)(u >> 16);
}
__device__ __forceinline__ float bf2f(unsigned short s) {
    return __uint_as_float(((unsigned int)s) << 16);
}
// physical col p (in a 128-wide interleaved buffer) -> logical col
__device__ __forceinline__ int permk(int p) {
    return (p & ~31) | ((p & 31) >> 1) | ((p & 1) << 4);
}

// ws layout (bytes)
#define WS_HBF  270336
#define WS_DEG  13070336
#define WS_ROW  13270336
#define WS_CUR  13470336
#define WS_BSUM 13670336
#define WS_RC2  13671360
#define WS_EAP  20071360

// ------------------------------------------------------------------ prep
__global__ void egnn_prep(const float* eW1, const float* eW2, const float* cW1,
                          const float* nW1, const float* nW2, const float* h,
                          const float* pos,
                          short* wsw, short* hbf, int* deg, float* out)
{
    int g = blockIdx.x * 256 + threadIdx.x;
    if (g < 16896) {
        const float* src; short* dst; int u, Kr, KC, mode;
        if (g < 4608)       { src = eW1; dst = wsw;            u = g;         Kr = 258; KC = 9;  mode = 0; }
        else if (g < 6656)  { src = eW2; dst = wsw + 4608*8;   u = g - 4608;  Kr = 128; KC = 4;  mode = 1; }
        else if (g < 8704)  { src = cW1; dst = wsw + 6656*8;   u = g - 6656;  Kr = 128; KC = 4;  mode = 1; }
        else if (g < 14848) { src = nW1; dst = wsw + 8704*8;   u = g - 8704;  Kr = 384; KC = 12; mode = 2; }
        else                { src = nW2; dst = wsw + 14848*8;  u = g - 14848; Kr = 128; KC = 4;  mode = 1; }
        int nt   = u / (KC * 64);
        int rem  = u % (KC * 64);
        int kc   = rem >> 6;
        int lane = rem & 63;
        int n    = nt * 16 + (lane & 15);
        int kb   = kc * 32 + ((lane >> 4) & 3) * 8;
        short8 o;
#pragma unroll
        for (int j = 0; j < 8; ++j) {
            int k = kb + j;
            int ks;
            if (mode == 0)      ks = k;
            else if (mode == 1) ks = permk(k);
            else {              // nW1: h natural, agg hi/lo permuted (lo reuses same rows)
                if (k < 128)      ks = k;
                else if (k < 256) ks = 128 + permk(k - 128);
                else              ks = 128 + permk(k - 256);
            }
            float v = (k < Kr) ? src[(long)ks * HID + n] : 0.0f;
            o[j] = (short)f2bf(v);
        }
        *(short8*)&dst[(long)u * 8] = o;
    } else if (g < 816896) {                       // h -> bf16
        long i = (long)(g - 16896) * 8;
        const float4 v0 = *(const float4*)&h[i];
        const float4 v1 = *(const float4*)&h[i + 4];
        uint4 o;
        o.x = pkbf(make_float2(v0.x, v0.y));
        o.y = pkbf(make_float2(v0.z, v0.w));
        o.z = pkbf(make_float2(v1.x, v1.y));
        o.w = pkbf(make_float2(v1.z, v1.w));
        *(uint4*)&hbf[i] = o;
    } else if (g < 2416896) {                      // zero agg region
        long i = (long)(g - 816896);
        ((float4*)out)[i] = make_float4(0.f, 0.f, 0.f, 0.f);
    } else if (g < 2566896) {                      // pos -> outpos
        int i = g - 2416896;
        out[(long)NNODE * HID + i] = pos[i];
    } else if (g < 2616896) {                      // zero deg
        int i = g - 2566896;
        deg[i] = 0;
    }
}

// ------------------------------------------------------------------ CSR build
__global__ void egnn_hist(const int* eidx, int* deg)
{
    int i = blockIdx.x * 256 + threadIdx.x;
    if (i < NEDGE / 4) {
        int4 v = ((const int4*)eidx)[i];
        atomicAdd(&deg[v.x], 1); atomicAdd(&deg[v.y], 1);
        atomicAdd(&deg[v.z], 1); atomicAdd(&deg[v.w], 1);
    }
}
__global__ void egnn_scan1(const int* deg, int* rowptr, int* bsum)
{
    __shared__ int s[256];
    int t = threadIdx.x, i = blockIdx.x * 256 + t;
    int v = (i < NNODE) ? deg[i] : 0;
    s[t] = v; __syncthreads();
    for (int o = 1; o < 256; o <<= 1) {
        int x = (t >= o) ? s[t - o] : 0;
        __syncthreads(); s[t] += x; __syncthreads();
    }
    if (i < NNODE) rowptr[i] = s[t] - v;
    if (t == 255) bsum[blockIdx.x] = s[t];
}
__global__ void egnn_scanF(int* rowptr, const int* bsum, int* cursor)
{
    __shared__ int red[256];
    int t = threadIdx.x, b = blockIdx.x;
    int acc = 0;
    for (int i = t; i < b; i += 256) acc += bsum[i];
    red[t] = acc; __syncthreads();
    for (int o = 128; o > 0; o >>= 1) {
        if (t < o) red[t] += red[t + o];
        __syncthreads();
    }
    int i = b * 256 + t;
    if (i < NNODE) cursor[i] = rowptr[i] + red[0];
}
// scatter: also pre-gather (row,col) and edge_attr into CSR-slot order,
// so the edge kernel has a single coalesced index-load level.
__global__ void egnn_scatter(const int* eidx, const float* ea, int* cursor,
                             int2* rc2, float* eap)
{
    int e = blockIdx.x * 256 + threadIdx.x;
    if (e < NEDGE) {
        int r = eidx[e], c = eidx[NEDGE + e];
        float a = ea[e];
        int p = atomicAdd(&cursor[r], 1);
        rc2[p] = make_int2(r, c);
        eap[p] = a;
    }
}

// ------------------------------------------------------------------ edge phase
__global__ __launch_bounds__(256, 4)
void egnn_edge(const short* hbf, const float* pos, const int2* rc2, const float* eap,
               const float* eb1, const float* eb2, const float* cb1,
               const float* cW2, const float* cb2,
               const short* eW1f, const short* eW2f, const short* cW1f,
               float* aggout, float* outpos)
{
    __shared__ __align__(16) short sX[EB * PX];   // unique h_rows -> bf16 m -> fp32 m (cols 0-63)
    __shared__ __align__(16) short sB[EB * PX];   // h_col -> silu(L1) -> fp32 m (cols 64-127)
    __shared__ int   rci[EB];
    __shared__ int   slotab[EB];   // per-edge unique-row slot
    __shared__ int   urow[EB];     // unique row ids
    __shared__ int   ucnt_s;
    __shared__ float rad[EB][4];
    __shared__ float ea_s[EB];
    __shared__ float part[EB][4];

    const int t  = threadIdx.x;
    const int e0 = blockIdx.x * EB;
    const int lane = t & 63;
    const int w    = t >> 6;
    const int l15  = lane & 15;
    const int q    = lane >> 4;
    const int ns   = w * 32;

    short8 bb[4][2];
    short8 a[4];
    f32x4 acc[2][4];
    float2 mreg2[4][4];

    // persisted wave-0 per-edge state (valid for t < EB)
    int   r_reg = 0, slot_reg = 0;
    float dxr = 0.f, dyr = 0.f, dzr = 0.f, rnr = 1.f;
    float prx = 0.f, pry = 0.f, prz = 0.f;   // pos[row] kept for exclusive-run stores

    // hoisted biases / weights (off the inter-barrier dependent chain)
    const float bv1a = eb1[ns + l15];
    const float bv1b = eb1[ns + 16 + l15];
    const float bv2a = eb2[ns + l15];
    const float bv2b = eb2[ns + 16 + l15];
    const float bv3a = cb1[ns + l15];
    const float bv3b = cb1[ns + 16 + l15];
    const float cw0  = cW2[ns + l15];
    const float cw1  = cW2[ns + 16 + l15];
    const float cb2v = cb2[0];

    // preload GEMM1 B-frags for the COL phase first (logical k 128..255 -> kc+4)
#pragma unroll
    for (int kc = 0; kc < 4; ++kc)
#pragma unroll
        for (int nt = 0; nt < 2; ++nt)
            bb[kc][nt] = *(const short8*)&eW1f[(((w * 2 + nt) * 9 + kc + 4) * 64 + lane) * 8];

    // P1: stage h[col]->sB (rows are dedup-staged after B1)
    {
        int2 rcv[4];
#pragma unroll
        for (int it = 0; it < 4; ++it) rcv[it] = rc2[e0 + (t >> 4) + it * 16];
        const int c16 = t & 15;
#pragma unroll
        for (int it = 0; it < 4; ++it) {
            int e = (t >> 4) + it * 16;
            *(uint4*)&sB[e * PX + c16 * 8] = *(const uint4*)&hbf[(long)rcv[it].y * HID + c16 * 8];
        }
    }
    // P0: wave 0 builds index tables, run-slot table, geometry
    if (t < EB) {
        int2 rc = rc2[e0 + t];
        int r = rc.x, c = rc.y;
        r_reg = r;
        rci[t] = r;
        ea_s[t] = eap[e0 + t];
        prx = pos[(long)r * 3 + 0]; pry = pos[(long)r * 3 + 1]; prz = pos[(long)r * 3 + 2];
        float dx = prx - pos[(long)c * 3 + 0];
        float dy = pry - pos[(long)c * 3 + 1];
        float dz = prz - pos[(long)c * 3 + 2];
        float rn = fmaxf(sqrtf(dx * dx + dy * dy + dz * dz), 1e-8f);
        dxr = dx; dyr = dy; dzr = dz; rnr = rn;
        rad[t][0] = dx; rad[t][1] = dy; rad[t][2] = dz; rad[t][3] = rn;
        int rprev = __shfl_up(r, 1);
        bool is_start = (t == 0) || (r != rprev);
        unsigned long long mask = __ballot(is_start);
        slot_reg = __popcll(mask << (63 - t)) - 1;   // rank of run containing edge t
        slotab[t] = slot_reg;
        if (is_start) urow[slot_reg] = r;
        if (t == 0) ucnt_s = __popcll(mask);
    }
    __syncthreads();   // B1: col staging + slot/urow tables visible

    // row staging: unique rows only (~5 typical, <=64 worst case)
    {
        const int c16 = t & 15;
        const int U = ucnt_s;
        for (int u = t >> 4; u < U; u += 16)
            *(uint4*)&sX[u * PX + c16 * 8] = *(const uint4*)&hbf[(long)urow[u] * HID + c16 * 8];
    }
    // per-thread slot lookup for A-frag indirection (broadcast reads)
    int sv[4];
#pragma unroll
    for (int mt = 0; mt < 4; ++mt) sv[mt] = slotab[mt * 16 + l15];

    // acc init
#pragma unroll
    for (int nt = 0; nt < 2; ++nt) {
        float bv = (nt == 0) ? bv1a : bv1b;
#pragma unroll
        for (int mt = 0; mt < 4; ++mt)
            for (int r = 0; r < 4; ++r) acc[nt][mt][r] = bv;
    }
    // GEMM1 phase A: col half (sB), logical k 128..255 — overlaps row-gather latency
#pragma unroll
    for (int kc = 0; kc < 4; ++kc) {
#pragma unroll
        for (int mt = 0; mt < 4; ++mt)
            a[mt] = *(const short8*)&sB[(mt * 16 + l15) * PX + kc * 32 + q * 8];
#pragma unroll
        for (int nt = 0; nt < 2; ++nt)
#pragma unroll
            for (int mt = 0; mt < 4; ++mt)
                acc[nt][mt] = __builtin_amdgcn_mfma_f32_16x16x32_bf16(a[mt], bb[kc][nt], acc[nt][mt], 0, 0, 0);
    }
    // preload row-half B-frags (logical k 0..127)
#pragma unroll
    for (int kc = 0; kc < 4; ++kc)
#pragma unroll
        for (int nt = 0; nt < 2; ++nt)
            bb[kc][nt] = *(const short8*)&eW1f[(((w * 2 + nt) * 9 + kc) * 64 + lane) * 8];
    __syncthreads();   // B2: dedup'd row staging visible

    // GEMM1 phase B: row half via slot indirection (same-slot lanes broadcast)
#pragma unroll
    for (int kc = 0; kc < 4; ++kc) {
#pragma unroll
        for (int mt = 0; mt < 4; ++mt)
            a[mt] = *(const short8*)&sX[sv[mt] * PX + kc * 32 + q * 8];
#pragma unroll
        for (int nt = 0; nt < 2; ++nt)
#pragma unroll
            for (int mt = 0; mt < 4; ++mt)
                acc[nt][mt] = __builtin_amdgcn_mfma_f32_16x16x32_bf16(a[mt], bb[kc][nt], acc[nt][mt], 0, 0, 0);
    }
    {   // kc8 tail: [rn, ea] columns
        short8 b8[2];
#pragma unroll
        for (int nt = 0; nt < 2; ++nt)
            b8[nt] = *(const short8*)&eW1f[(((w * 2 + nt) * 9 + 8) * 64 + lane) * 8];
#pragma unroll
        for (int mt = 0; mt < 4; ++mt) {
            int row = mt * 16 + l15;
            short8 a8;
#pragma unroll
            for (int j = 0; j < 8; ++j) a8[j] = 0;
            if (q == 0) {
                a8[0] = (short)f2bf(rad[row][3]);
                a8[1] = (short)f2bf(ea_s[row]);
            }
            a[mt] = a8;
        }
#pragma unroll
        for (int nt = 0; nt < 2; ++nt)
#pragma unroll
            for (int mt = 0; mt < 4; ++mt)
                acc[nt][mt] = __builtin_amdgcn_mfma_f32_16x16x32_bf16(a[mt], b8[nt], acc[nt][mt], 0, 0, 0);
    }
    // preload GEMM2 B-frags
#pragma unroll
    for (int kc = 0; kc < 4; ++kc)
#pragma unroll
        for (int nt = 0; nt < 2; ++nt)
            bb[kc][nt] = *(const short8*)&eW2f[(((w * 2 + nt) * 4 + kc) * 64 + lane) * 8];

    // GEMM1 epilogue: silu -> sB (all sB readers finished before B2; writes are per-wave disjoint)
#pragma unroll
    for (int mt = 0; mt < 4; ++mt)
#pragma unroll
        for (int r = 0; r < 4; ++r) {
            float2 v = silu2(acc[0][mt][r], acc[1][mt][r]);
            *(unsigned int*)&sB[(mt * 16 + q * 4 + r) * PX + ns + 2 * l15] = pkbf(v);
        }
    __syncthreads();   // B5

    // P5: GEMM2: sB @ eW2f -> silu = m (float2 regs + interleaved bf16 into sX)
#pragma unroll
    for (int nt = 0; nt < 2; ++nt) {
        float bv = (nt == 0) ? bv2a : bv2b;
#pragma unroll
        for (int mt = 0; mt < 4; ++mt)
            for (int r = 0; r < 4; ++r) acc[nt][mt][r] = bv;
    }
#pragma unroll
    for (int kc = 0; kc < 4; ++kc) {
#pragma unroll
        for (int mt = 0; mt < 4; ++mt)
            a[mt] = *(const short8*)&sB[(mt * 16 + l15) * PX + kc * 32 + q * 8];
#pragma unroll
        for (int nt = 0; nt < 2; ++nt)
#pragma unroll
            for (int mt = 0; mt < 4; ++mt)
                acc[nt][mt] = __builtin_amdgcn_mfma_f32_16x16x32_bf16(a[mt], bb[kc][nt], acc[nt][mt], 0, 0, 0);
    }
    // preload GEMM3 B-frags
#pragma unroll
    for (int kc = 0; kc < 4; ++kc)
#pragma unroll
        for (int nt = 0; nt < 2; ++nt)
            bb[kc][nt] = *(const short8*)&cW1f[(((w * 2 + nt) * 4 + kc) * 64 + lane) * 8];
#pragma unroll
    for (int mt = 0; mt < 4; ++mt)
#pragma unroll
        for (int r = 0; r < 4; ++r) {
            float2 v = silu2(acc[0][mt][r], acc[1][mt][r]);
            mreg2[mt][r] = v;
            *(unsigned int*)&sX[(mt * 16 + q * 4 + r) * PX + ns + 2 * l15] = pkbf(v);
        }
    __syncthreads();   // B6

    // P6: GEMM3: m @ cW1f -> silu -> dot(cW2) -> part
#pragma unroll
    for (int nt = 0; nt < 2; ++nt) {
        float bv = (nt == 0) ? bv3a : bv3b;
#pragma unroll
        for (int mt = 0; mt < 4; ++mt)
            for (int r = 0; r < 4; ++r) acc[nt][mt][r] = bv;
    }
#pragma unroll
    for (int kc = 0; kc < 4; ++kc) {
#pragma unroll
        for (int mt = 0; mt < 4; ++mt)
            a[mt] = *(const short8*)&sX[(mt * 16 + l15) * PX + kc * 32 + q * 8];
#pragma unroll
        for (int nt = 0; nt < 2; ++nt)
#pragma unroll
            for (int mt = 0; mt < 4; ++mt)
                acc[nt][mt] = __builtin_amdgcn_mfma_f32_16x16x32_bf16(a[mt], bb[kc][nt], acc[nt][mt], 0, 0, 0);
    }
    {
#pragma unroll
        for (int mt = 0; mt < 4; ++mt) {
            float p[4];
            for (int r = 0; r < 4; ++r) {
                float2 s = silu2(acc[0][mt][r], acc[1][mt][r]);
                p[r] = s.x * cw0 + s.y * cw1;
            }
            for (int mask = 1; mask < 16; mask <<= 1)
                for (int r = 0; r < 4; ++r) p[r] += __shfl_xor(p[r], mask);
            if (l15 == 0)
                for (int r = 0; r < 4; ++r) part[mt * 16 + q * 4 + r][w] = p[r];
        }
    }
    __syncthreads();   // B7

    // P7: fp32 m dump as float2 (waves 0,1 -> sX, waves 2,3 -> sB) + merged pos updates
    {
        float2* dst = (w < 2) ? (float2*)sX : (float2*)sB;
        int cp = w * 16 + l15 - ((w < 2) ? 0 : 32);
#pragma unroll
        for (int mt = 0; mt < 4; ++mt)
#pragma unroll
            for (int r = 0; r < 4; ++r)
                dst[(mt * 16 + q * 4 + r) * 34 + cp] = mreg2[mt][r];
    }
    if (t < EB) {
        float cd  = part[t][0] + part[t][1] + part[t][2] + part[t][3] + cb2v;
        float inv = cd / rnr;
        float px = inv * dxr, py = inv * dyr, pz = inv * dzr;
        // segmented inclusive sum over same-row runs (wave 0 only)
        int sl = slot_reg;
#pragma unroll
        for (int off = 1; off < 64; off <<= 1) {
            float ux = __shfl_up(px, off);
            float uy = __shfl_up(py, off);
            float uz = __shfl_up(pz, off);
            int   su = __shfl_up(sl, off);
            if (t >= off && su == sl) { px += ux; py += uy; pz += uz; }
        }
        int snx = __shfl_down(sl, 1);
        if (t == 63 || snx != sl) {      // last edge of run
            if (sl >= 1 && t != 63) {
                // run started AND ended inside this block -> globally exclusive:
                // plain store of pos + sum (outpos pre-initialized to pos by prep)
                outpos[(long)r_reg * 3 + 0] = prx + px;
                outpos[(long)r_reg * 3 + 1] = pry + py;
                outpos[(long)r_reg * 3 + 2] = prz + pz;
            } else {
                atomicAdd(&outpos[(long)r_reg * 3 + 0], px);
                atomicAdd(&outpos[(long)r_reg * 3 + 1], py);
                atomicAdd(&outpos[(long)r_reg * 3 + 2], pz);
            }
        }
    }
    __syncthreads();   // B8

    // P8: run-merged agg: thread = (colpair, edge-quarter), kq = t>>6 WAVE-UNIFORM.
    // Runs strictly interior to a quarter are globally exclusive (CSR contiguity)
    // -> plain store into the zeroed agg buffer; boundary runs stay atomic.
    {
        int cpg = t & 63;                 // colpair: phys cols (2*cpg, 2*cpg+1)
        int kq  = t >> 6;                 // edge quarter (uniform across the wave)
        const float2* srcf = (cpg < 32) ? (const float2*)sX : (const float2*)sB;
        int cp = cpg & 31;
        long j0 = 2 * cpg;
        float s0 = 0.0f, s1 = 0.0f;
        int prev = rci[16 * kq];
        bool first = true;                // first flush may belong to a run extending backward
        for (int e = 16 * kq; e < 16 * kq + 16; ++e) {
            int rr = rci[e];
            if (rr != prev) {
                if (first) {
                    atomicAdd(&aggout[(long)prev * HID + j0], s0);
                    atomicAdd(&aggout[(long)prev * HID + j0 + 1], s1);
                    first = false;
                } else {
                    aggout[(long)prev * HID + j0]     = s0;
                    aggout[(long)prev * HID + j0 + 1] = s1;
                }
                s0 = 0.0f; s1 = 0.0f; prev = rr;
            }
            float2 v = srcf[e * 34 + cp];
            s0 += v.x; s1 += v.y;
        }
        atomicAdd(&aggout[(long)prev * HID + j0], s0);      // may extend forward
        atomicAdd(&aggout[(long)prev * HID + j0 + 1], s1);
    }
}

// ------------------------------------------------------------------ node phase (agg aliases out h-region)
// sB2 aliases sA (written only after all GEMM1 reads of sA) -> LDS 50.2KB -> 3 blocks/CU
__global__ __launch_bounds__(256, 3)
void egnn_node(const float* h, const short* hbf, const float* agg,
               const float* nb1, const float* nb2,
               const short* nW1f, const short* nW2f,
               float* out)
{
    __shared__ __align__(16) short sA[EB * PN];
    short* sB2 = sA;   // alias: epilogue writes gated by a barrier after GEMM1

    const int t  = threadIdx.x;
    const int n0 = blockIdx.x * EB;

    for (int i = t; i < EB * 16; i += 256) {
        int e = i >> 4, uu = i & 15;
        int nd = n0 + e; if (nd >= NNODE) nd = NNODE - 1;
        *(uint4*)&sA[e * PN + uu * 8] = *(const uint4*)&hbf[(long)nd * HID + uu * 8];
    }
    for (int i = t; i < EB * 32; i += 256) {
        int e = i >> 5, uu = i & 31;
        int nd = n0 + e; if (nd >= NNODE) nd = NNODE - 1;
        const float4 v = *(const float4*)&agg[(long)nd * HID + uu * 4];
        unsigned int h0 = pkbf(make_float2(v.x, v.y));
        unsigned int h1 = pkbf(make_float2(v.z, v.w));
        *(uint2*)&sA[e * PN + HID + uu * 4] = make_uint2(h0, h1);
        unsigned int l0 = pkbf(make_float2(v.x - bf2f((unsigned short)h0),
                                           v.y - bf2f((unsigned short)(h0 >> 16))));
        unsigned int l1 = pkbf(make_float2(v.z - bf2f((unsigned short)h1),
                                           v.w - bf2f((unsigned short)(h1 >> 16))));
        *(uint2*)&sA[e * PN + 2 * HID + uu * 4] = make_uint2(l0, l1);
    }
    __syncthreads();

    const int lane = t & 63;
    const int w    = t >> 6;
    const int l15  = lane & 15;
    const int q    = lane >> 4;
    const int ns   = w * 32;

    f32x4 acc[2][4];
    short8 a[4], b[2];

#pragma unroll
    for (int nt = 0; nt < 2; ++nt) {
        float bv = nb1[ns + nt * 16 + l15];
#pragma unroll
        for (int mt = 0; mt < 4; ++mt)
            for (int r = 0; r < 4; ++r) acc[nt][mt][r] = bv;
    }
#pragma unroll
    for (int kc = 0; kc < 12; ++kc) {
#pragma unroll
        for (int mt = 0; mt < 4; ++mt)
            a[mt] = *(const short8*)&sA[(mt * 16 + l15) * PN + kc * 32 + q * 8];
#pragma unroll
        for (int nt = 0; nt < 2; ++nt)
            b[nt] = *(const short8*)&nW1f[(((w * 2 + nt) * 12 + kc) * 64 + lane) * 8];
#pragma unroll
        for (int nt = 0; nt < 2; ++nt)
#pragma unroll
            for (int mt = 0; mt < 4; ++mt)
                acc[nt][mt] = __builtin_amdgcn_mfma_f32_16x16x32_bf16(a[mt], b[nt], acc[nt][mt], 0, 0, 0);
    }
    __syncthreads();   // all sA reads done -> safe to overwrite via sB2 alias
#pragma unroll
    for (int mt = 0; mt < 4; ++mt)
#pragma unroll
        for (int r = 0; r < 4; ++r) {
            float2 v = silu2(acc[0][mt][r], acc[1][mt][r]);
            *(unsigned int*)&sB2[(mt * 16 + q * 4 + r) * PX + ns + 2 * l15] = pkbf(v);
        }
    __syncthreads();

#pragma unroll
    for (int nt = 0; nt < 2; ++nt) {
        float bv = nb2[ns + nt * 16 + l15];
#pragma unroll
        for (int mt = 0; mt < 4; ++mt)
            for (int r = 0; r < 4; ++r) acc[nt][mt][r] = bv;
    }
#pragma unroll
    for (int kc = 0; kc < 4; ++kc) {
#pragma unroll
        for (int mt = 0; mt < 4; ++mt)
            a[mt] = *(const short8*)&sB2[(mt * 16 + l15) * PX + kc * 32 + q * 8];
#pragma unroll
        for (int nt = 0; nt < 2; ++nt)
            b[nt] = *(const short8*)&nW2f[(((w * 2 + nt) * 4 + kc) * 64 + lane) * 8];
#pragma unroll
        for (int nt = 0; nt < 2; ++nt)
#pragma unroll
            for (int mt = 0; mt < 4; ++mt)
                acc[nt][mt] = __builtin_amdgcn_mfma_f32_16x16x32_bf16(a[mt], b[nt], acc[nt][mt], 0, 0, 0);
    }
#pragma unroll
    for (int nt = 0; nt < 2; ++nt)
#pragma unroll
        for (int mt = 0; mt < 4; ++mt)
            for (int r = 0; r < 4; ++r) {
                int m  = mt * 16 + q * 4 + r;
                int nd = n0 + m;
                if (nd < NNODE) {
                    int n = ns + nt * 16 + l15;
                    out[(long)nd * HID + n] = h[(long)nd * HID + n] + acc[nt][mt][r];
                }
            }
}

// ------------------------------------------------------------------ launch
extern "C" void kernel_launch(void* const* d_in, const int* in_sizes, int n_in,
                              void* d_out, int out_size, void* d_ws, size_t ws_size,
                              hipStream_t stream)
{
    const float* h    = (const float*)d_in[0];
    const float* pos  = (const float*)d_in[1];
    const float* ea   = (const float*)d_in[2];
    const int*   eidx = (const int*)d_in[3];
    const float* eW1  = (const float*)d_in[4];
    const float* eb1  = (const float*)d_in[5];
    const float* eW2  = (const float*)d_in[6];
    const float* eb2  = (const float*)d_in[7];
    const float* nW1  = (const float*)d_in[8];
    const float* nb1  = (const float*)d_in[9];
    const float* nW2  = (const float*)d_in[10];
    const float* nb2  = (const float*)d_in[11];
    const float* cW1  = (const float*)d_in[12];
    const float* cb1  = (const float*)d_in[13];
    const float* cW2  = (const float*)d_in[14];
    const float* cb2  = (const float*)d_in[15];

    float* out    = (float*)d_out;
    float* outpos = out + (long)NNODE * HID;

    char* ws = (char*)d_ws;
    short* wsw    = (short*)ws;
    short* hbf    = (short*)(ws + WS_HBF);
    int*   deg    = (int*)(ws + WS_DEG);
    int*   rowptr = (int*)(ws + WS_ROW);
    int*   cursor = (int*)(ws + WS_CUR);
    int*   bsum   = (int*)(ws + WS_BSUM);
    int2*  rc2    = (int2*)(ws + WS_RC2);
    float* eap    = (float*)(ws + WS_EAP);

    const short* eW1f = wsw;
    const short* eW2f = wsw + 4608 * 8;
    const short* cW1f = wsw + 6656 * 8;
    const short* nW1f = wsw + 8704 * 8;
    const short* nW2f = wsw + 14848 * 8;

    egnn_prep<<<(2616896 + 255) / 256, 256, 0, stream>>>(
        eW1, eW2, cW1, nW1, nW2, h, pos, wsw, hbf, deg, out);
    egnn_hist<<<(NEDGE / 4 + 255) / 256, 256, 0, stream>>>(eidx, deg);
    egnn_scan1<<<196, 256, 0, stream>>>(deg, rowptr, bsum);
    egnn_scanF<<<196, 256, 0, stream>>>(rowptr, bsum, cursor);
    egnn_scatter<<<(NEDGE + 255) / 256, 256, 0, stream>>>(eidx, ea, cursor, rc2, eap);
    egnn_edge<<<NEDGE / EB, 256, 0, stream>>>(hbf, pos, rc2, eap,
                                              eb1, eb2, cb1, cW2, cb2,
                                              eW1f, eW2f, cW1f, out, outpos);
    egnn_node<<<(NNODE + EB - 1) / EB, 256, 0, stream>>>(h, hbf, out, nb1, nb2,
                                                         nW1f, nW2f, out);
}

// Round 9
// 405.934 us; speedup vs baseline: 1.4050x; 1.0063x over previous
//
#include <hip/hip_runtime.h>
#include <hip/hip_bf16.h>
#include <math.h>

#define HID   128
#define NNODE 50000
#define NEDGE 800000
#define EB    64
#define PX    136   // edge/intermediate pitch (shorts) = 68 dwords = 34 float2
#define PN    392   // node featA pitch (shorts): [h | agg_hi | agg_lo]

typedef __attribute__((ext_vector_type(8))) short short8;
typedef __attribute__((ext_vector_type(4))) float f32x4;

__device__ __forceinline__ float2 silu2(float x, float y) {
    return make_float2(x * __builtin_amdgcn_rcpf(1.0f + __expf(-x)),
                       y * __builtin_amdgcn_rcpf(1.0f + __expf(-y)));
}
__device__ __forceinline__ unsigned int pkbf(float2 v) {   // packed RNE f32x2 -> bf16x2
    __hip_bfloat162 b2 = __float22bfloat162_rn(v);
    return *(unsigned int*)&b2;
}
__device__ __forceinline__ unsigned short f2bf(float f) {  // scalar RNE
    unsigned int u = __float_as_uint(f);
    u += 0x7FFFu + ((u >> 16) & 1u);
    return (unsigned short)(u >> 16);
}
__device__ __forceinline__ float bf2f(unsigned short s) {
    return __uint_as_float(((unsigned int)s) << 16);
}
// physical col p (in a 128-wide interleaved buffer) -> logical col
__device__ __forceinline__ int permk(int p) {
    return (p & ~31) | ((p & 31) >> 1) | ((p & 1) << 4);
}

// ws layout (bytes)
#define WS_HBF  270336
#define WS_DEG  13070336
#define WS_ROW  13270336
#define WS_CUR  13470336
#define WS_BSUM 13670336
#define WS_RC2  13671360
#define WS_EAP  20071360

// ------------------------------------------------------------------ prep
__global__ void egnn_prep(const float* eW1, const float* eW2, const float* cW1,
                          const float* nW1, const float* nW2, const float* h,
                          const float* pos,
                          short* wsw, short* hbf, int* deg, float* out)
{
    int g = blockIdx.x * 256 + threadIdx.x;
    if (g < 16896) {
        const float* src; short* dst; int u, Kr, KC, mode;
        if (g < 4608)       { src = eW1; dst = wsw;            u = g;         Kr = 258; KC = 9;  mode = 0; }
        else if (g < 6656)  { src = eW2; dst = wsw + 4608*8;   u = g - 4608;  Kr = 128; KC = 4;  mode = 1; }
        else if (g < 8704)  { src = cW1; dst = wsw + 6656*8;   u = g - 6656;  Kr = 128; KC = 4;  mode = 1; }
        else if (g < 14848) { src = nW1; dst = wsw + 8704*8;   u = g - 8704;  Kr = 384; KC = 12; mode = 2; }
        else                { src = nW2; dst = wsw + 14848*8;  u = g - 14848; Kr = 128; KC = 4;  mode = 1; }
        int nt   = u / (KC * 64);
        int rem  = u % (KC * 64);
        int kc   = rem >> 6;
        int lane = rem & 63;
        int n    = nt * 16 + (lane & 15);
        int kb   = kc * 32 + ((lane >> 4) & 3) * 8;
        short8 o;
#pragma unroll
        for (int j = 0; j < 8; ++j) {
            int k = kb + j;
            int ks;
            if (mode == 0)      ks = k;
            else if (mode == 1) ks = permk(k);
            else {              // nW1: h natural, agg hi/lo permuted (lo reuses same rows)
                if (k < 128)      ks = k;
                else if (k < 256) ks = 128 + permk(k - 128);
                else              ks = 128 + permk(k - 256);
            }
            float v = (k < Kr) ? src[(long)ks * HID + n] : 0.0f;
            o[j] = (short)f2bf(v);
        }
        *(short8*)&dst[(long)u * 8] = o;
    } else if (g < 816896) {                       // h -> bf16
        long i = (long)(g - 16896) * 8;
        const float4 v0 = *(const float4*)&h[i];
        const float4 v1 = *(const float4*)&h[i + 4];
        uint4 o;
        o.x = pkbf(make_float2(v0.x, v0.y));
        o.y = pkbf(make_float2(v0.z, v0.w));
        o.z = pkbf(make_float2(v1.x, v1.y));
        o.w = pkbf(make_float2(v1.z, v1.w));
        *(uint4*)&hbf[i] = o;
    } else if (g < 2416896) {                      // zero agg region
        long i = (long)(g - 816896);
        ((float4*)out)[i] = make_float4(0.f, 0.f, 0.f, 0.f);
    } else if (g < 2566896) {                      // pos -> outpos
        int i = g - 2416896;
        out[(long)NNODE * HID + i] = pos[i];
    } else if (g < 2616896) {                      // zero deg
        int i = g - 2566896;
        deg[i] = 0;
    }
}

// ------------------------------------------------------------------ CSR build
__global__ void egnn_hist(const int* eidx, int* deg)
{
    int i = blockIdx.x * 256 + threadIdx.x;
    if (i < NEDGE / 4) {
        int4 v = ((const int4*)eidx)[i];
        atomicAdd(&deg[v.x], 1); atomicAdd(&deg[v.y], 1);
        atomicAdd(&deg[v.z], 1); atomicAdd(&deg[v.w], 1);
    }
}
__global__ void egnn_scan1(const int* deg, int* rowptr, int* bsum)
{
    __shared__ int s[256];
    int t = threadIdx.x, i = blockIdx.x * 256 + t;
    int v = (i < NNODE) ? deg[i] : 0;
    s[t] = v; __syncthreads();
    for (int o = 1; o < 256; o <<= 1) {
        int x = (t >= o) ? s[t - o] : 0;
        __syncthreads(); s[t] += x; __syncthreads();
    }
    if (i < NNODE) rowptr[i] = s[t] - v;
    if (t == 255) bsum[blockIdx.x] = s[t];
}
__global__ void egnn_scanF(int* rowptr, const int* bsum, int* cursor)
{
    __shared__ int red[256];
    int t = threadIdx.x, b = blockIdx.x;
    int acc = 0;
    for (int i = t; i < b; i += 256) acc += bsum[i];
    red[t] = acc; __syncthreads();
    for (int o = 128; o > 0; o >>= 1) {
        if (t < o) red[t] += red[t + o];
        __syncthreads();
    }
    int i = b * 256 + t;
    if (i < NNODE) cursor[i] = rowptr[i] + red[0];
}
// scatter: also pre-gather (row,col) and edge_attr into CSR-slot order,
// so the edge kernel has a single coalesced index-load level.
__global__ void egnn_scatter(const int* eidx, const float* ea, int* cursor,
                             int2* rc2, float* eap)
{
    int e = blockIdx.x * 256 + threadIdx.x;
    if (e < NEDGE) {
        int r = eidx[e], c = eidx[NEDGE + e];
        float a = ea[e];
        int p = atomicAdd(&cursor[r], 1);
        rc2[p] = make_int2(r, c);
        eap[p] = a;
    }
}

// ------------------------------------------------------------------ edge phase
__global__ __launch_bounds__(256, 4)
void egnn_edge(const short* hbf, const float* pos, const int2* rc2, const float* eap,
               const float* eb1, const float* eb2, const float* cb1,
               const float* cW2, const float* cb2,
               const short* eW1f, const short* eW2f, const short* cW1f,
               float* aggout, float* outpos)
{
    __shared__ __align__(16) short sX[EB * PX];   // unique h_rows -> bf16 m -> fp32 m (cols 0-63)
    __shared__ __align__(16) short sB[EB * PX];   // h_col -> silu(L1) -> fp32 m (cols 64-127)
    __shared__ int   rci[EB];
    __shared__ int   slotab[EB];   // per-edge unique-row slot
    __shared__ int   urow[EB];     // unique row ids
    __shared__ int   ucnt_s;
    __shared__ float rad[EB][4];
    __shared__ float ea_s[EB];
    __shared__ float part[EB][4];

    const int t  = threadIdx.x;
    const int e0 = blockIdx.x * EB;
    const int lane = t & 63;
    const int w    = t >> 6;
    const int l15  = lane & 15;
    const int q    = lane >> 4;
    const int ns   = w * 32;

    short8 bb[4][2];
    short8 a[4];
    f32x4 acc[2][4];
    float2 mreg2[4][4];

    // persisted wave-0 per-edge state (valid for t < EB)
    int   r_reg = 0, slot_reg = 0;
    float dxr = 0.f, dyr = 0.f, dzr = 0.f, rnr = 1.f;

    // hoisted biases / weights (off the inter-barrier dependent chain)
    const float bv1a = eb1[ns + l15];
    const float bv1b = eb1[ns + 16 + l15];
    const float bv2a = eb2[ns + l15];
    const float bv2b = eb2[ns + 16 + l15];
    const float bv3a = cb1[ns + l15];
    const float bv3b = cb1[ns + 16 + l15];
    const float cw0  = cW2[ns + l15];
    const float cw1  = cW2[ns + 16 + l15];
    const float cb2v = cb2[0];

    // preload GEMM1 B-frags for the COL phase first (logical k 128..255 -> kc+4)
#pragma unroll
    for (int kc = 0; kc < 4; ++kc)
#pragma unroll
        for (int nt = 0; nt < 2; ++nt)
            bb[kc][nt] = *(const short8*)&eW1f[(((w * 2 + nt) * 9 + kc + 4) * 64 + lane) * 8];

    // P1: stage h[col]->sB (rows are dedup-staged after B1)
    {
        int2 rcv[4];
#pragma unroll
        for (int it = 0; it < 4; ++it) rcv[it] = rc2[e0 + (t >> 4) + it * 16];
        const int c16 = t & 15;
#pragma unroll
        for (int it = 0; it < 4; ++it) {
            int e = (t >> 4) + it * 16;
            *(uint4*)&sB[e * PX + c16 * 8] = *(const uint4*)&hbf[(long)rcv[it].y * HID + c16 * 8];
        }
    }
    // P0: wave 0 builds index tables, run-slot table, geometry
    if (t < EB) {
        int2 rc = rc2[e0 + t];
        int r = rc.x, c = rc.y;
        r_reg = r;
        rci[t] = r;
        ea_s[t] = eap[e0 + t];
        float dx = pos[(long)r * 3 + 0] - pos[(long)c * 3 + 0];
        float dy = pos[(long)r * 3 + 1] - pos[(long)c * 3 + 1];
        float dz = pos[(long)r * 3 + 2] - pos[(long)c * 3 + 2];
        float rn = fmaxf(sqrtf(dx * dx + dy * dy + dz * dz), 1e-8f);
        dxr = dx; dyr = dy; dzr = dz; rnr = rn;
        rad[t][0] = dx; rad[t][1] = dy; rad[t][2] = dz; rad[t][3] = rn;
        int rprev = __shfl_up(r, 1);
        bool is_start = (t == 0) || (r != rprev);
        unsigned long long mask = __ballot(is_start);
        slot_reg = __popcll(mask << (63 - t)) - 1;   // rank of run containing edge t
        slotab[t] = slot_reg;
        if (is_start) urow[slot_reg] = r;
        if (t == 0) ucnt_s = __popcll(mask);
    }
    __syncthreads();   // B1: col staging + slot/urow tables visible

    // row staging: unique rows only (~5 typical, <=64 worst case)
    {
        const int c16 = t & 15;
        const int U = ucnt_s;
        for (int u = t >> 4; u < U; u += 16)
            *(uint4*)&sX[u * PX + c16 * 8] = *(const uint4*)&hbf[(long)urow[u] * HID + c16 * 8];
    }
    // per-thread slot lookup for A-frag indirection (broadcast reads)
    int sv[4];
#pragma unroll
    for (int mt = 0; mt < 4; ++mt) sv[mt] = slotab[mt * 16 + l15];

    // acc init
#pragma unroll
    for (int nt = 0; nt < 2; ++nt) {
        float bv = (nt == 0) ? bv1a : bv1b;
#pragma unroll
        for (int mt = 0; mt < 4; ++mt)
            for (int r = 0; r < 4; ++r) acc[nt][mt][r] = bv;
    }
    // GEMM1 phase A: col half (sB), logical k 128..255 — overlaps row-gather latency
#pragma unroll
    for (int kc = 0; kc < 4; ++kc) {
#pragma unroll
        for (int mt = 0; mt < 4; ++mt)
            a[mt] = *(const short8*)&sB[(mt * 16 + l15) * PX + kc * 32 + q * 8];
#pragma unroll
        for (int nt = 0; nt < 2; ++nt)
#pragma unroll
            for (int mt = 0; mt < 4; ++mt)
                acc[nt][mt] = __builtin_amdgcn_mfma_f32_16x16x32_bf16(a[mt], bb[kc][nt], acc[nt][mt], 0, 0, 0);
    }
    // preload row-half B-frags (logical k 0..127)
#pragma unroll
    for (int kc = 0; kc < 4; ++kc)
#pragma unroll
        for (int nt = 0; nt < 2; ++nt)
            bb[kc][nt] = *(const short8*)&eW1f[(((w * 2 + nt) * 9 + kc) * 64 + lane) * 8];
    __syncthreads();   // B2: dedup'd row staging visible

    // GEMM1 phase B: row half via slot indirection (same-slot lanes broadcast)
#pragma unroll
    for (int kc = 0; kc < 4; ++kc) {
#pragma unroll
        for (int mt = 0; mt < 4; ++mt)
            a[mt] = *(const short8*)&sX[sv[mt] * PX + kc * 32 + q * 8];
#pragma unroll
        for (int nt = 0; nt < 2; ++nt)
#pragma unroll
            for (int mt = 0; mt < 4; ++mt)
                acc[nt][mt] = __builtin_amdgcn_mfma_f32_16x16x32_bf16(a[mt], bb[kc][nt], acc[nt][mt], 0, 0, 0);
    }
    {   // kc8 tail: [rn, ea] columns
        short8 b8[2];
#pragma unroll
        for (int nt = 0; nt < 2; ++nt)
            b8[nt] = *(const short8*)&eW1f[(((w * 2 + nt) * 9 + 8) * 64 + lane) * 8];
#pragma unroll
        for (int mt = 0; mt < 4; ++mt) {
            int row = mt * 16 + l15;
            short8 a8;
#pragma unroll
            for (int j = 0; j < 8; ++j) a8[j] = 0;
            if (q == 0) {
                a8[0] = (short)f2bf(rad[row][3]);
                a8[1] = (short)f2bf(ea_s[row]);
            }
            a[mt] = a8;
        }
#pragma unroll
        for (int nt = 0; nt < 2; ++nt)
#pragma unroll
            for (int mt = 0; mt < 4; ++mt)
                acc[nt][mt] = __builtin_amdgcn_mfma_f32_16x16x32_bf16(a[mt], b8[nt], acc[nt][mt], 0, 0, 0);
    }
    // preload GEMM2 B-frags
#pragma unroll
    for (int kc = 0; kc < 4; ++kc)
#pragma unroll
        for (int nt = 0; nt < 2; ++nt)
            bb[kc][nt] = *(const short8*)&eW2f[(((w * 2 + nt) * 4 + kc) * 64 + lane) * 8];

    // GEMM1 epilogue: silu -> sB (all sB readers finished before B2; writes are per-wave disjoint)
#pragma unroll
    for (int mt = 0; mt < 4; ++mt)
#pragma unroll
        for (int r = 0; r < 4; ++r) {
            float2 v = silu2(acc[0][mt][r], acc[1][mt][r]);
            *(unsigned int*)&sB[(mt * 16 + q * 4 + r) * PX + ns + 2 * l15] = pkbf(v);
        }
    __syncthreads();   // B5

    // P5: GEMM2: sB @ eW2f -> silu = m (float2 regs + interleaved bf16 into sX)
#pragma unroll
    for (int nt = 0; nt < 2; ++nt) {
        float bv = (nt == 0) ? bv2a : bv2b;
#pragma unroll
        for (int mt = 0; mt < 4; ++mt)
            for (int r = 0; r < 4; ++r) acc[nt][mt][r] = bv;
    }
#pragma unroll
    for (int kc = 0; kc < 4; ++kc) {
#pragma unroll
        for (int mt = 0; mt < 4; ++mt)
            a[mt] = *(const short8*)&sB[(mt * 16 + l15) * PX + kc * 32 + q * 8];
#pragma unroll
        for (int nt = 0; nt < 2; ++nt)
#pragma unroll
            for (int mt = 0; mt < 4; ++mt)
                acc[nt][mt] = __builtin_amdgcn_mfma_f32_16x16x32_bf16(a[mt], bb[kc][nt], acc[nt][mt], 0, 0, 0);
    }
    // preload GEMM3 B-frags
#pragma unroll
    for (int kc = 0; kc < 4; ++kc)
#pragma unroll
        for (int nt = 0; nt < 2; ++nt)
            bb[kc][nt] = *(const short8*)&cW1f[(((w * 2 + nt) * 4 + kc) * 64 + lane) * 8];
#pragma unroll
    for (int mt = 0; mt < 4; ++mt)
#pragma unroll
        for (int r = 0; r < 4; ++r) {
            float2 v = silu2(acc[0][mt][r], acc[1][mt][r]);
            mreg2[mt][r] = v;
            *(unsigned int*)&sX[(mt * 16 + q * 4 + r) * PX + ns + 2 * l15] = pkbf(v);
        }
    __syncthreads();   // B6

    // P6: GEMM3: m @ cW1f -> silu -> dot(cW2) -> part
#pragma unroll
    for (int nt = 0; nt < 2; ++nt) {
        float bv = (nt == 0) ? bv3a : bv3b;
#pragma unroll
        for (int mt = 0; mt < 4; ++mt)
            for (int r = 0; r < 4; ++r) acc[nt][mt][r] = bv;
    }
#pragma unroll
    for (int kc = 0; kc < 4; ++kc) {
#pragma unroll
        for (int mt = 0; mt < 4; ++mt)
            a[mt] = *(const short8*)&sX[(mt * 16 + l15) * PX + kc * 32 + q * 8];
#pragma unroll
        for (int nt = 0; nt < 2; ++nt)
#pragma unroll
            for (int mt = 0; mt < 4; ++mt)
                acc[nt][mt] = __builtin_amdgcn_mfma_f32_16x16x32_bf16(a[mt], bb[kc][nt], acc[nt][mt], 0, 0, 0);
    }
    {
#pragma unroll
        for (int mt = 0; mt < 4; ++mt) {
            float p[4];
            for (int r = 0; r < 4; ++r) {
                float2 s = silu2(acc[0][mt][r], acc[1][mt][r]);
                p[r] = s.x * cw0 + s.y * cw1;
            }
            for (int mask = 1; mask < 16; mask <<= 1)
                for (int r = 0; r < 4; ++r) p[r] += __shfl_xor(p[r], mask);
            if (l15 == 0)
                for (int r = 0; r < 4; ++r) part[mt * 16 + q * 4 + r][w] = p[r];
        }
    }
    __syncthreads();   // B7

    // P7: fp32 m dump as float2 (waves 0,1 -> sX, waves 2,3 -> sB) + merged pos atomics
    {
        float2* dst = (w < 2) ? (float2*)sX : (float2*)sB;
        int cp = w * 16 + l15 - ((w < 2) ? 0 : 32);
#pragma unroll
        for (int mt = 0; mt < 4; ++mt)
#pragma unroll
            for (int r = 0; r < 4; ++r)
                dst[(mt * 16 + q * 4 + r) * 34 + cp] = mreg2[mt][r];
    }
    if (t < EB) {
        float cd  = part[t][0] + part[t][1] + part[t][2] + part[t][3] + cb2v;
        float inv = cd / rnr;
        float px = inv * dxr, py = inv * dyr, pz = inv * dzr;
        // segmented inclusive sum over same-row runs (wave 0 only)
        int sl = slot_reg;
#pragma unroll
        for (int off = 1; off < 64; off <<= 1) {
            float ux = __shfl_up(px, off);
            float uy = __shfl_up(py, off);
            float uz = __shfl_up(pz, off);
            int   su = __shfl_up(sl, off);
            if (t >= off && su == sl) { px += ux; py += uy; pz += uz; }
        }
        int snx = __shfl_down(sl, 1);
        if (t == 63 || snx != sl) {      // last edge of run -> one atomic triple per run
            atomicAdd(&outpos[(long)r_reg * 3 + 0], px);
            atomicAdd(&outpos[(long)r_reg * 3 + 1], py);
            atomicAdd(&outpos[(long)r_reg * 3 + 2], pz);
        }
    }
    __syncthreads();   // B8

    // P8: run-merged agg atomics: thread = (colpair, edge-quarter), kq = t>>6 is
    // WAVE-UNIFORM (critical: uniform boundary branches, coherent flush atomics).
    // All flushes are atomicAdd: scattered plain stores regressed (R8: write-allocate
    // line fetch + dirty churn, +20MB WRITE, +6us) — atomics execute memory-side at L2.
    {
        int cpg = t & 63;                 // colpair: phys cols (2*cpg, 2*cpg+1)
        int kq  = t >> 6;                 // edge quarter (uniform across the wave)
        const float2* srcf = (cpg < 32) ? (const float2*)sX : (const float2*)sB;
        int cp = cpg & 31;
        long j0 = 2 * cpg;
        float s0 = 0.0f, s1 = 0.0f;
        int prev = rci[16 * kq];
        for (int e = 16 * kq; e < 16 * kq + 16; ++e) {
            int rr = rci[e];
            if (rr != prev) {
                atomicAdd(&aggout[(long)prev * HID + j0], s0);
                atomicAdd(&aggout[(long)prev * HID + j0 + 1], s1);
                s0 = 0.0f; s1 = 0.0f; prev = rr;
            }
            float2 v = srcf[e * 34 + cp];
            s0 += v.x; s1 += v.y;
        }
        atomicAdd(&aggout[(long)prev * HID + j0], s0);
        atomicAdd(&aggout[(long)prev * HID + j0 + 1], s1);
    }
}

// ------------------------------------------------------------------ node phase (agg aliases out h-region)
// sB2 aliases sA (written only after all GEMM1 reads of sA) -> LDS 50.2KB -> 3 blocks/CU
__global__ __launch_bounds__(256, 3)
void egnn_node(const float* h, const short* hbf, const float* agg,
               const float* nb1, const float* nb2,
               const short* nW1f, const short* nW2f,
               float* out)
{
    __shared__ __align__(16) short sA[EB * PN];
    short* sB2 = sA;   // alias: epilogue writes gated by a barrier after GEMM1

    const int t  = threadIdx.x;
    const int n0 = blockIdx.x * EB;

    for (int i = t; i < EB * 16; i += 256) {
        int e = i >> 4, uu = i & 15;
        int nd = n0 + e; if (nd >= NNODE) nd = NNODE - 1;
        *(uint4*)&sA[e * PN + uu * 8] = *(const uint4*)&hbf[(long)nd * HID + uu * 8];
    }
    for (int i = t; i < EB * 32; i += 256) {
        int e = i >> 5, uu = i & 31;
        int nd = n0 + e; if (nd >= NNODE) nd = NNODE - 1;
        const float4 v = *(const float4*)&agg[(long)nd * HID + uu * 4];
        unsigned int h0 = pkbf(make_float2(v.x, v.y));
        unsigned int h1 = pkbf(make_float2(v.z, v.w));
        *(uint2*)&sA[e * PN + HID + uu * 4] = make_uint2(h0, h1);
        unsigned int l0 = pkbf(make_float2(v.x - bf2f((unsigned short)h0),
                                           v.y - bf2f((unsigned short)(h0 >> 16))));
        unsigned int l1 = pkbf(make_float2(v.z - bf2f((unsigned short)h1),
                                           v.w - bf2f((unsigned short)(h1 >> 16))));
        *(uint2*)&sA[e * PN + 2 * HID + uu * 4] = make_uint2(l0, l1);
    }
    __syncthreads();

    const int lane = t & 63;
    const int w    = t >> 6;
    const int l15  = lane & 15;
    const int q    = lane >> 4;
    const int ns   = w * 32;

    f32x4 acc[2][4];
    short8 a[4], b[2];

#pragma unroll
    for (int nt = 0; nt < 2; ++nt) {
        float bv = nb1[ns + nt * 16 + l15];
#pragma unroll
        for (int mt = 0; mt < 4; ++mt)
            for (int r = 0; r < 4; ++r) acc[nt][mt][r] = bv;
    }
#pragma unroll
    for (int kc = 0; kc < 12; ++kc) {
#pragma unroll
        for (int mt = 0; mt < 4; ++mt)
            a[mt] = *(const short8*)&sA[(mt * 16 + l15) * PN + kc * 32 + q * 8];
#pragma unroll
        for (int nt = 0; nt < 2; ++nt)
            b[nt] = *(const short8*)&nW1f[(((w * 2 + nt) * 12 + kc) * 64 + lane) * 8];
#pragma unroll
        for (int nt = 0; nt < 2; ++nt)
#pragma unroll
            for (int mt = 0; mt < 4; ++mt)
                acc[nt][mt] = __builtin_amdgcn_mfma_f32_16x16x32_bf16(a[mt], b[nt], acc[nt][mt], 0, 0, 0);
    }
    __syncthreads();   // all sA reads done -> safe to overwrite via sB2 alias
#pragma unroll
    for (int mt = 0; mt < 4; ++mt)
#pragma unroll
        for (int r = 0; r < 4; ++r) {
            float2 v = silu2(acc[0][mt][r], acc[1][mt][r]);
            *(unsigned int*)&sB2[(mt * 16 + q * 4 + r) * PX + ns + 2 * l15] = pkbf(v);
        }
    __syncthreads();

#pragma unroll
    for (int nt = 0; nt < 2; ++nt) {
        float bv = nb2[ns + nt * 16 + l15];
#pragma unroll
        for (int mt = 0; mt < 4; ++mt)
            for (int r = 0; r < 4; ++r) acc[nt][mt][r] = bv;
    }
#pragma unroll
    for (int kc = 0; kc < 4; ++kc) {
#pragma unroll
        for (int mt = 0; mt < 4; ++mt)
            a[mt] = *(const short8*)&sB2[(mt * 16 + l15) * PX + kc * 32 + q * 8];
#pragma unroll
        for (int nt = 0; nt < 2; ++nt)
            b[nt] = *(const short8*)&nW2f[(((w * 2 + nt) * 4 + kc) * 64 + lane) * 8];
#pragma unroll
        for (int nt = 0; nt < 2; ++nt)
#pragma unroll
            for (int mt = 0; mt < 4; ++mt)
                acc[nt][mt] = __builtin_amdgcn_mfma_f32_16x16x32_bf16(a[mt], b[nt], acc[nt][mt], 0, 0, 0);
    }
#pragma unroll
    for (int nt = 0; nt < 2; ++nt)
#pragma unroll
        for (int mt = 0; mt < 4; ++mt)
            for (int r = 0; r < 4; ++r) {
                int m  = mt * 16 + q * 4 + r;
                int nd = n0 + m;
                if (nd < NNODE) {
                    int n = ns + nt * 16 + l15;
                    out[(long)nd * HID + n] = h[(long)nd * HID + n] + acc[nt][mt][r];
                }
            }
}

// ------------------------------------------------------------------ launch
extern "C" void kernel_launch(void* const* d_in, const int* in_sizes, int n_in,
                              void* d_out, int out_size, void* d_ws, size_t ws_size,
                              hipStream_t stream)
{
    const float* h    = (const float*)d_in[0];
    const float* pos  = (const float*)d_in[1];
    const float* ea   = (const float*)d_in[2];
    const int*   eidx = (const int*)d_in[3];
    const float* eW1  = (const float*)d_in[4];
    const float* eb1  = (const float*)d_in[5];
    const float* eW2  = (const float*)d_in[6];
    const float* eb2  = (const float*)d_in[7];
    const float* nW1  = (const float*)d_in[8];
    const float* nb1  = (const float*)d_in[9];
    const float* nW2  = (const float*)d_in[10];
    const float* nb2  = (const float*)d_in[11];
    const float* cW1  = (const float*)d_in[12];
    const float* cb1  = (const float*)d_in[13];
    const float* cW2  = (const float*)d_in[14];
    const float* cb2  = (const float*)d_in[15];

    float* out    = (float*)d_out;
    float* outpos = out + (long)NNODE * HID;

    char* ws = (char*)d_ws;
    short* wsw    = (short*)ws;
    short* hbf    = (short*)(ws + WS_HBF);
    int*   deg    = (int*)(ws + WS_DEG);
    int*   rowptr = (int*)(ws + WS_ROW);
    int*   cursor = (int*)(ws + WS_CUR);
    int*   bsum   = (int*)(ws + WS_BSUM);
    int2*  rc2    = (int2*)(ws + WS_RC2);
    float* eap    = (float*)(ws + WS_EAP);

    const short* eW1f = wsw;
    const short* eW2f = wsw + 4608 * 8;
    const short* cW1f = wsw + 6656 * 8;
    const short* nW1f = wsw + 8704 * 8;
    const short* nW2f = wsw + 14848 * 8;

    egnn_prep<<<(2616896 + 255) / 256, 256, 0, stream>>>(
        eW1, eW2, cW1, nW1, nW2, h, pos, wsw, hbf, deg, out);
    egnn_hist<<<(NEDGE / 4 + 255) / 256, 256, 0, stream>>>(eidx, deg);
    egnn_scan1<<<196, 256, 0, stream>>>(deg, rowptr, bsum);
    egnn_scanF<<<196, 256, 0, stream>>>(rowptr, bsum, cursor);
    egnn_scatter<<<(NEDGE + 255) / 256, 256, 0, stream>>>(eidx, ea, cursor, rc2, eap);
    egnn_edge<<<NEDGE / EB, 256, 0, stream>>>(hbf, pos, rc2, eap,
                                              eb1, eb2, cb1, cW2, cb2,
                                              eW1f, eW2f, cW1f, out, outpos);
    egnn_node<<<(NNODE + EB - 1) / EB, 256, 0, stream>>>(h, hbf, out, nb1, nb2,
                                                         nW1f, nW2f, out);
}